// Round 1
// baseline (1209.337 us; speedup 1.0000x reference)
//
#include <hip/hip_runtime.h>
#include <math.h>

#define N_USERS   50000
#define N_ENT     100000
#define N_EDGES   2000000
#define NNZ       1000000
#define DIM       64
#define N_HOPS    3

// ---------------- CSR build ----------------

__global__ void hist_kernel(const int* __restrict__ key, int n, int* __restrict__ cnt) {
    int i = blockIdx.x * blockDim.x + threadIdx.x;
    int stride = gridDim.x * blockDim.x;
    for (; i < n; i += stride) atomicAdd(&cnt[key[i]], 1);
}

__global__ void scan_partial(const int* __restrict__ cnt, int n, int* __restrict__ bsum) {
    __shared__ int sd[256];
    int tid = threadIdx.x, i = blockIdx.x * 256 + tid;
    sd[tid] = (i < n) ? cnt[i] : 0;
    __syncthreads();
    for (int s = 128; s > 0; s >>= 1) {
        if (tid < s) sd[tid] += sd[tid + s];
        __syncthreads();
    }
    if (tid == 0) bsum[blockIdx.x] = sd[0];
}

// single block, exclusive scan of up to 1024 block sums (in place)
__global__ void scan_bsum(int* bsum, int nb) {
    __shared__ int sd[1024];
    int tid = threadIdx.x;
    int v = (tid < nb) ? bsum[tid] : 0;
    sd[tid] = v;
    __syncthreads();
    for (int o = 1; o < 1024; o <<= 1) {
        int t = (tid >= o) ? sd[tid - o] : 0;
        __syncthreads();
        sd[tid] += t;
        __syncthreads();
    }
    if (tid < nb) bsum[tid] = sd[tid] - v;  // exclusive
}

__global__ void scan_final(const int* __restrict__ cnt, int n,
                           const int* __restrict__ bsum, int* __restrict__ rp) {
    __shared__ int sd[256];
    int tid = threadIdx.x, i = blockIdx.x * 256 + tid;
    int v = (i < n) ? cnt[i] : 0;
    sd[tid] = v;
    __syncthreads();
    for (int o = 1; o < 256; o <<= 1) {
        int t = (tid >= o) ? sd[tid - o] : 0;
        __syncthreads();
        sd[tid] += t;
        __syncthreads();
    }
    int incl = sd[tid] + bsum[blockIdx.x];
    if (i < n) rp[i] = incl - v;       // exclusive prefix
    if (i == n - 1) rp[n] = incl;      // total
}

// scatter KG edges into CSR order, packing (tail | (etype-1)<<20) + unmask
__global__ void scatter_edges(const int* __restrict__ head, const int* __restrict__ tail,
                              const int* __restrict__ etype, const float* __restrict__ unmask,
                              int n, int* __restrict__ cur,
                              int* __restrict__ packed_s, float* __restrict__ w_s) {
    int i = blockIdx.x * blockDim.x + threadIdx.x;
    if (i < n) {
        int pos = atomicAdd(&cur[head[i]], 1);
        packed_s[pos] = tail[i] | ((etype[i] - 1) << 20);
        w_s[pos] = unmask[i];
    }
}

// scatter interaction cols into CSR order (store col value directly)
__global__ void scatter_cols(const int* __restrict__ rows, const int* __restrict__ cols,
                             int n, int* __restrict__ cur, int* __restrict__ col_s) {
    int i = blockIdx.x * blockDim.x + threadIdx.x;
    if (i < n) {
        int pos = atomicAdd(&cur[rows[i]], 1);
        col_s[pos] = cols[i];
    }
}

// ---------------- per-hop aggregate + normalize + residual ----------------
// one 64-lane wave per output row; lane = dim

__global__ __launch_bounds__(256) void agg_entity(
    const float* __restrict__ ent_in, const float* __restrict__ weight,
    const int* __restrict__ rp, const int* __restrict__ packed_s,
    const float* __restrict__ w_s, float* __restrict__ ent_out,
    float* __restrict__ res, int n_rows) {
    int wave = (blockIdx.x * blockDim.x + threadIdx.x) >> 6;
    int lane = threadIdx.x & 63;
    if (wave >= n_rows) return;
    int beg = rp[wave], end = rp[wave + 1];
    float acc = 0.f;
    for (int p = beg; p < end; ++p) {
        int pk = packed_s[p];
        int t = pk & 0xFFFFF;
        int rt = pk >> 20;
        float sc = w_s[p];
        float rel = weight[rt * DIM + lane];
        acc = fmaf(ent_in[(size_t)t * DIM + lane] * sc, rel, acc);
    }
    float ss = acc * acc;
#pragma unroll
    for (int o = 32; o > 0; o >>= 1) ss += __shfl_xor(ss, o, 64);
    float out = acc / fmaxf(sqrtf(ss), 1e-12f);
    size_t idx = (size_t)wave * DIM + lane;
    ent_out[idx] = out;
    res[idx] += out;
}

__global__ __launch_bounds__(256) void agg_user(
    const float* __restrict__ ent_in, const int* __restrict__ rp,
    const int* __restrict__ col_s, float* __restrict__ res, int n_rows) {
    int wave = (blockIdx.x * blockDim.x + threadIdx.x) >> 6;
    int lane = threadIdx.x & 63;
    if (wave >= n_rows) return;
    int beg = rp[wave], end = rp[wave + 1];
    float acc = 0.f;
    for (int p = beg; p < end; ++p) {
        int c = col_s[p];
        acc += ent_in[(size_t)c * DIM + lane];
    }
    float ss = acc * acc;
#pragma unroll
    for (int o = 32; o > 0; o >>= 1) ss += __shfl_xor(ss, o, 64);
    float out = acc / fmaxf(sqrtf(ss), 1e-12f);
    res[(size_t)wave * DIM + lane] += out;
}

// ---------------- launch ----------------

extern "C" void kernel_launch(void* const* d_in, const int* in_sizes, int n_in,
                              void* d_out, int out_size, void* d_ws, size_t ws_size,
                              hipStream_t stream) {
    const float* user_emb   = (const float*)d_in[0];
    const float* entity_emb = (const float*)d_in[1];
    const float* weight     = (const float*)d_in[2];
    const float* unmask     = (const float*)d_in[3];
    const int*   edge_index = (const int*)d_in[4];
    const int*   edge_type  = (const int*)d_in[5];
    const int*   irows      = (const int*)d_in[6];
    const int*   icols      = (const int*)d_in[7];
    const int* head = edge_index;            // edge_index[0]
    const int* tail = edge_index + N_EDGES;  // edge_index[1]

    char* ws = (char*)d_ws;
    size_t off = 0;
    auto alloc = [&](size_t bytes) -> void* {
        void* p = ws + off;
        off += (bytes + 255) & ~(size_t)255;
        return p;
    };
    float* ent_a    = (float*)alloc((size_t)N_ENT * DIM * 4);
    float* ent_b    = (float*)alloc((size_t)N_ENT * DIM * 4);
    int*   rp_e     = (int*)alloc((N_ENT + 1) * 4);
    int*   cur_e    = (int*)alloc(N_ENT * 4);          // counts, then cursor
    int*   packed_s = (int*)alloc((size_t)N_EDGES * 4);
    float* w_s      = (float*)alloc((size_t)N_EDGES * 4);
    int*   rp_u     = (int*)alloc((N_USERS + 1) * 4);
    int*   cur_u    = (int*)alloc(N_USERS * 4);
    int*   col_s    = (int*)alloc((size_t)NNZ * 4);
    int*   bs_e     = (int*)alloc(1024 * 4);
    int*   bs_u     = (int*)alloc(1024 * 4);
    (void)ws_size;

    // --- CSR build (same every call; deterministic up to f32 sum order) ---
    hipMemsetAsync(cur_e, 0, N_ENT * 4, stream);
    hipMemsetAsync(cur_u, 0, N_USERS * 4, stream);
    hist_kernel<<<2048, 256, 0, stream>>>(head, N_EDGES, cur_e);
    hist_kernel<<<1024, 256, 0, stream>>>(irows, NNZ, cur_u);

    int nb_e = (N_ENT + 255) / 256;    // 391
    int nb_u = (N_USERS + 255) / 256;  // 196
    scan_partial<<<nb_e, 256, 0, stream>>>(cur_e, N_ENT, bs_e);
    scan_bsum<<<1, 1024, 0, stream>>>(bs_e, nb_e);
    scan_final<<<nb_e, 256, 0, stream>>>(cur_e, N_ENT, bs_e, rp_e);
    scan_partial<<<nb_u, 256, 0, stream>>>(cur_u, N_USERS, bs_u);
    scan_bsum<<<1, 1024, 0, stream>>>(bs_u, nb_u);
    scan_final<<<nb_u, 256, 0, stream>>>(cur_u, N_USERS, bs_u, rp_u);

    hipMemcpyAsync(cur_e, rp_e, N_ENT * 4, hipMemcpyDeviceToDevice, stream);
    hipMemcpyAsync(cur_u, rp_u, N_USERS * 4, hipMemcpyDeviceToDevice, stream);
    scatter_edges<<<(N_EDGES + 255) / 256, 256, 0, stream>>>(
        head, tail, edge_type, unmask, N_EDGES, cur_e, packed_s, w_s);
    scatter_cols<<<(NNZ + 255) / 256, 256, 0, stream>>>(
        irows, icols, NNZ, cur_u, col_s);

    // --- init residuals ---
    float* res_e = (float*)d_out;
    float* res_u = res_e + (size_t)N_ENT * DIM;
    hipMemcpyAsync(res_e, entity_emb, (size_t)N_ENT * DIM * 4, hipMemcpyDeviceToDevice, stream);
    hipMemcpyAsync(res_u, user_emb, (size_t)N_USERS * DIM * 4, hipMemcpyDeviceToDevice, stream);

    // --- 3 hops ---
    const float* ent_in = entity_emb;
    float* bufs[2] = {ent_a, ent_b};
    for (int h = 0; h < N_HOPS; ++h) {
        float* ent_out = bufs[h & 1];
        agg_entity<<<(N_ENT + 3) / 4, 256, 0, stream>>>(
            ent_in, weight, rp_e, packed_s, w_s, ent_out, res_e, N_ENT);
        agg_user<<<(N_USERS + 3) / 4, 256, 0, stream>>>(
            ent_in, rp_u, col_s, res_u, N_USERS);
        ent_in = ent_out;
    }
}

// Round 2
// 745.796 us; speedup vs baseline: 1.6215x; 1.6215x over previous
//
#include <hip/hip_runtime.h>
#include <math.h>

#define N_USERS   50000
#define N_ENT     100000
#define N_EDGES   2000000
#define NNZ       1000000
#define DIM       64
#define N_HOPS    3

// ---------------- CSR build ----------------

__global__ void hist_kernel(const int* __restrict__ key, int n, int* __restrict__ cnt) {
    int i = blockIdx.x * blockDim.x + threadIdx.x;
    int stride = gridDim.x * blockDim.x;
    for (; i < n; i += stride) atomicAdd(&cnt[key[i]], 1);
}

__global__ void scan_partial(const int* __restrict__ cnt, int n, int* __restrict__ bsum) {
    __shared__ int sd[256];
    int tid = threadIdx.x, i = blockIdx.x * 256 + tid;
    sd[tid] = (i < n) ? cnt[i] : 0;
    __syncthreads();
    for (int s = 128; s > 0; s >>= 1) {
        if (tid < s) sd[tid] += sd[tid + s];
        __syncthreads();
    }
    if (tid == 0) bsum[blockIdx.x] = sd[0];
}

// single block, exclusive scan of up to 1024 block sums (in place)
__global__ void scan_bsum(int* bsum, int nb) {
    __shared__ int sd[1024];
    int tid = threadIdx.x;
    int v = (tid < nb) ? bsum[tid] : 0;
    sd[tid] = v;
    __syncthreads();
    for (int o = 1; o < 1024; o <<= 1) {
        int t = (tid >= o) ? sd[tid - o] : 0;
        __syncthreads();
        sd[tid] += t;
        __syncthreads();
    }
    if (tid < nb) bsum[tid] = sd[tid] - v;  // exclusive
}

__global__ void scan_final(const int* __restrict__ cnt, int n,
                           const int* __restrict__ bsum, int* __restrict__ rp) {
    __shared__ int sd[256];
    int tid = threadIdx.x, i = blockIdx.x * 256 + tid;
    int v = (i < n) ? cnt[i] : 0;
    sd[tid] = v;
    __syncthreads();
    for (int o = 1; o < 256; o <<= 1) {
        int t = (tid >= o) ? sd[tid - o] : 0;
        __syncthreads();
        sd[tid] += t;
        __syncthreads();
    }
    int incl = sd[tid] + bsum[blockIdx.x];
    if (i < n) rp[i] = incl - v;       // exclusive prefix
    if (i == n - 1) rp[n] = incl;      // total
}

// scatter KG edges into CSR order, packing (tail | (etype-1)<<20) + unmask
__global__ void scatter_edges(const int* __restrict__ head, const int* __restrict__ tail,
                              const int* __restrict__ etype, const float* __restrict__ unmask,
                              int n, int* __restrict__ cur,
                              int* __restrict__ packed_s, float* __restrict__ w_s) {
    int i = blockIdx.x * blockDim.x + threadIdx.x;
    if (i < n) {
        int pos = atomicAdd(&cur[head[i]], 1);
        packed_s[pos] = tail[i] | ((etype[i] - 1) << 20);
        w_s[pos] = unmask[i];
    }
}

// scatter interaction cols into CSR order (store col value directly)
__global__ void scatter_cols(const int* __restrict__ rows, const int* __restrict__ cols,
                             int n, int* __restrict__ cur, int* __restrict__ col_s) {
    int i = blockIdx.x * blockDim.x + threadIdx.x;
    if (i < n) {
        int pos = atomicAdd(&cur[rows[i]], 1);
        col_s[pos] = cols[i];
    }
}

// ---------------- per-hop aggregate + normalize + residual ----------------
// one 64-lane wave per output row; 4 groups of 16 lanes each gather a
// DIFFERENT edge's 256B row (float4/lane) -> 4 gathers in flight per wave.

__global__ __launch_bounds__(256) void agg_entity(
    const float4* __restrict__ ent_in, const float4* __restrict__ weight4,
    const int* __restrict__ rp, const int* __restrict__ packed_s,
    const float* __restrict__ w_s, float4* __restrict__ ent_out,
    float4* __restrict__ res, int n_rows) {
    int wave = (blockIdx.x * blockDim.x + threadIdx.x) >> 6;
    int lane = threadIdx.x & 63;
    if (wave >= n_rows) return;
    int grp = lane >> 4;   // edge slot 0..3
    int sub = lane & 15;   // float4 index within row
    int beg = rp[wave], end = rp[wave + 1];
    float ax = 0.f, ay = 0.f, az = 0.f, aw = 0.f;
    for (int p0 = beg; p0 < end; p0 += 4) {
        int pe = p0 + grp;
        int pk = 0;
        float sc = 0.f;
        if (pe < end) { pk = packed_s[pe]; sc = w_s[pe]; }
        int t  = pk & 0xFFFFF;
        int rt = (pk >> 20) & 15;
        float4 row = ent_in[(size_t)t * 16 + sub];
        float4 rel = weight4[rt * 16 + sub];
        ax = fmaf(row.x * sc, rel.x, ax);
        ay = fmaf(row.y * sc, rel.y, ay);
        az = fmaf(row.z * sc, rel.z, az);
        aw = fmaf(row.w * sc, rel.w, aw);
    }
    // fold the 4 edge slots (lanes differing in bits 4,5)
#pragma unroll
    for (int o = 16; o < 64; o <<= 1) {
        ax += __shfl_xor(ax, o, 64);
        ay += __shfl_xor(ay, o, 64);
        az += __shfl_xor(az, o, 64);
        aw += __shfl_xor(aw, o, 64);
    }
    float ss = ax * ax + ay * ay + az * az + aw * aw;
#pragma unroll
    for (int o = 1; o < 16; o <<= 1) ss += __shfl_xor(ss, o, 64);
    float inv = 1.0f / fmaxf(sqrtf(ss), 1e-12f);
    if (lane < 16) {
        size_t idx = (size_t)wave * 16 + sub;
        float4 o4 = { ax * inv, ay * inv, az * inv, aw * inv };
        ent_out[idx] = o4;
        float4 r = res[idx];
        r.x += o4.x; r.y += o4.y; r.z += o4.z; r.w += o4.w;
        res[idx] = r;
    }
}

__global__ __launch_bounds__(256) void agg_user(
    const float4* __restrict__ ent_in, const int* __restrict__ rp,
    const int* __restrict__ col_s, float4* __restrict__ res, int n_rows) {
    int wave = (blockIdx.x * blockDim.x + threadIdx.x) >> 6;
    int lane = threadIdx.x & 63;
    if (wave >= n_rows) return;
    int grp = lane >> 4;
    int sub = lane & 15;
    int beg = rp[wave], end = rp[wave + 1];
    float ax = 0.f, ay = 0.f, az = 0.f, aw = 0.f;
    for (int p0 = beg; p0 < end; p0 += 4) {
        int pe = p0 + grp;
        int c = 0;
        float m = 0.f;
        if (pe < end) { c = col_s[pe]; m = 1.f; }
        float4 row = ent_in[(size_t)c * 16 + sub];
        ax = fmaf(row.x, m, ax);
        ay = fmaf(row.y, m, ay);
        az = fmaf(row.z, m, az);
        aw = fmaf(row.w, m, aw);
    }
#pragma unroll
    for (int o = 16; o < 64; o <<= 1) {
        ax += __shfl_xor(ax, o, 64);
        ay += __shfl_xor(ay, o, 64);
        az += __shfl_xor(az, o, 64);
        aw += __shfl_xor(aw, o, 64);
    }
    float ss = ax * ax + ay * ay + az * az + aw * aw;
#pragma unroll
    for (int o = 1; o < 16; o <<= 1) ss += __shfl_xor(ss, o, 64);
    float inv = 1.0f / fmaxf(sqrtf(ss), 1e-12f);
    if (lane < 16) {
        size_t idx = (size_t)wave * 16 + sub;
        float4 r = res[idx];
        r.x = fmaf(ax, inv, r.x);
        r.y = fmaf(ay, inv, r.y);
        r.z = fmaf(az, inv, r.z);
        r.w = fmaf(aw, inv, r.w);
        res[idx] = r;
    }
}

// ---------------- launch ----------------

extern "C" void kernel_launch(void* const* d_in, const int* in_sizes, int n_in,
                              void* d_out, int out_size, void* d_ws, size_t ws_size,
                              hipStream_t stream) {
    const float* user_emb   = (const float*)d_in[0];
    const float* entity_emb = (const float*)d_in[1];
    const float* weight     = (const float*)d_in[2];
    const float* unmask     = (const float*)d_in[3];
    const int*   edge_index = (const int*)d_in[4];
    const int*   edge_type  = (const int*)d_in[5];
    const int*   irows      = (const int*)d_in[6];
    const int*   icols      = (const int*)d_in[7];
    const int* head = edge_index;            // edge_index[0]
    const int* tail = edge_index + N_EDGES;  // edge_index[1]

    char* ws = (char*)d_ws;
    size_t off = 0;
    auto alloc = [&](size_t bytes) -> void* {
        void* p = ws + off;
        off += (bytes + 255) & ~(size_t)255;
        return p;
    };
    float* ent_a    = (float*)alloc((size_t)N_ENT * DIM * 4);
    float* ent_b    = (float*)alloc((size_t)N_ENT * DIM * 4);
    int*   rp_e     = (int*)alloc((N_ENT + 1) * 4);
    int*   cur_e    = (int*)alloc(N_ENT * 4);          // counts, then cursor
    int*   packed_s = (int*)alloc((size_t)N_EDGES * 4);
    float* w_s      = (float*)alloc((size_t)N_EDGES * 4);
    int*   rp_u     = (int*)alloc((N_USERS + 1) * 4);
    int*   cur_u    = (int*)alloc(N_USERS * 4);
    int*   col_s    = (int*)alloc((size_t)NNZ * 4);
    int*   bs_e     = (int*)alloc(1024 * 4);
    int*   bs_u     = (int*)alloc(1024 * 4);
    (void)ws_size;

    // --- CSR build (same every call; deterministic up to f32 sum order) ---
    hipMemsetAsync(cur_e, 0, N_ENT * 4, stream);
    hipMemsetAsync(cur_u, 0, N_USERS * 4, stream);
    hist_kernel<<<2048, 256, 0, stream>>>(head, N_EDGES, cur_e);
    hist_kernel<<<1024, 256, 0, stream>>>(irows, NNZ, cur_u);

    int nb_e = (N_ENT + 255) / 256;    // 391
    int nb_u = (N_USERS + 255) / 256;  // 196
    scan_partial<<<nb_e, 256, 0, stream>>>(cur_e, N_ENT, bs_e);
    scan_bsum<<<1, 1024, 0, stream>>>(bs_e, nb_e);
    scan_final<<<nb_e, 256, 0, stream>>>(cur_e, N_ENT, bs_e, rp_e);
    scan_partial<<<nb_u, 256, 0, stream>>>(cur_u, N_USERS, bs_u);
    scan_bsum<<<1, 1024, 0, stream>>>(bs_u, nb_u);
    scan_final<<<nb_u, 256, 0, stream>>>(cur_u, N_USERS, bs_u, rp_u);

    hipMemcpyAsync(cur_e, rp_e, N_ENT * 4, hipMemcpyDeviceToDevice, stream);
    hipMemcpyAsync(cur_u, rp_u, N_USERS * 4, hipMemcpyDeviceToDevice, stream);
    scatter_edges<<<(N_EDGES + 255) / 256, 256, 0, stream>>>(
        head, tail, edge_type, unmask, N_EDGES, cur_e, packed_s, w_s);
    scatter_cols<<<(NNZ + 255) / 256, 256, 0, stream>>>(
        irows, icols, NNZ, cur_u, col_s);

    // --- init residuals ---
    float* res_e = (float*)d_out;
    float* res_u = res_e + (size_t)N_ENT * DIM;
    hipMemcpyAsync(res_e, entity_emb, (size_t)N_ENT * DIM * 4, hipMemcpyDeviceToDevice, stream);
    hipMemcpyAsync(res_u, user_emb, (size_t)N_USERS * DIM * 4, hipMemcpyDeviceToDevice, stream);

    // --- 3 hops ---
    const float* ent_in = entity_emb;
    float* bufs[2] = {ent_a, ent_b};
    for (int h = 0; h < N_HOPS; ++h) {
        float* ent_out = bufs[h & 1];
        agg_entity<<<(N_ENT + 3) / 4, 256, 0, stream>>>(
            (const float4*)ent_in, (const float4*)weight,
            rp_e, packed_s, w_s,
            (float4*)ent_out, (float4*)res_e, N_ENT);
        agg_user<<<(N_USERS + 3) / 4, 256, 0, stream>>>(
            (const float4*)ent_in, rp_u, col_s, (float4*)res_u, N_USERS);
        ent_in = ent_out;
    }
}

// Round 3
// 693.786 us; speedup vs baseline: 1.7431x; 1.0750x over previous
//
#include <hip/hip_runtime.h>
#include <math.h>

#define N_USERS   50000
#define N_ENT     100000
#define N_EDGES   2000000
#define NNZ       1000000
#define DIM       64
#define N_HOPS    3

// ---------------- CSR build ----------------

__global__ void hist_kernel(const int* __restrict__ key, int n, int* __restrict__ cnt) {
    int i = blockIdx.x * blockDim.x + threadIdx.x;
    int stride = gridDim.x * blockDim.x;
    for (; i < n; i += stride) atomicAdd(&cnt[key[i]], 1);
}

__global__ void scan_partial(const int* __restrict__ cnt, int n, int* __restrict__ bsum) {
    __shared__ int sd[256];
    int tid = threadIdx.x, i = blockIdx.x * 256 + tid;
    sd[tid] = (i < n) ? cnt[i] : 0;
    __syncthreads();
    for (int s = 128; s > 0; s >>= 1) {
        if (tid < s) sd[tid] += sd[tid + s];
        __syncthreads();
    }
    if (tid == 0) bsum[blockIdx.x] = sd[0];
}

// single block, exclusive scan of up to 1024 block sums (in place)
__global__ void scan_bsum(int* bsum, int nb) {
    __shared__ int sd[1024];
    int tid = threadIdx.x;
    int v = (tid < nb) ? bsum[tid] : 0;
    sd[tid] = v;
    __syncthreads();
    for (int o = 1; o < 1024; o <<= 1) {
        int t = (tid >= o) ? sd[tid - o] : 0;
        __syncthreads();
        sd[tid] += t;
        __syncthreads();
    }
    if (tid < nb) bsum[tid] = sd[tid] - v;  // exclusive
}

// writes exclusive prefix to BOTH rp and cur (cursor copy fused)
__global__ void scan_final(const int* __restrict__ cnt, int n,
                           const int* __restrict__ bsum, int* __restrict__ rp,
                           int* __restrict__ cur) {
    __shared__ int sd[256];
    int tid = threadIdx.x, i = blockIdx.x * 256 + tid;
    int v = (i < n) ? cnt[i] : 0;
    sd[tid] = v;
    __syncthreads();
    for (int o = 1; o < 256; o <<= 1) {
        int t = (tid >= o) ? sd[tid - o] : 0;
        __syncthreads();
        sd[tid] += t;
        __syncthreads();
    }
    int incl = sd[tid] + bsum[blockIdx.x];
    if (i < n) {
        int excl = incl - v;
        rp[i]  = excl;
        cur[i] = excl;
    }
    if (i == n - 1) rp[n] = incl;      // total
}

// scatter KG edges into CSR order; single 8B store: (tail | rt<<20, unmask bits)
__global__ void scatter_edges(const int* __restrict__ head, const int* __restrict__ tail,
                              const int* __restrict__ etype, const float* __restrict__ unmask,
                              int n, int* __restrict__ cur, int2* __restrict__ ev) {
    int i = blockIdx.x * blockDim.x + threadIdx.x;
    if (i < n) {
        int pos = atomicAdd(&cur[head[i]], 1);
        ev[pos] = make_int2(tail[i] | ((etype[i] - 1) << 20), __float_as_int(unmask[i]));
    }
}

// scatter interaction cols into CSR order
__global__ void scatter_cols(const int* __restrict__ rows, const int* __restrict__ cols,
                             int n, int* __restrict__ cur, int* __restrict__ col_s) {
    int i = blockIdx.x * blockDim.x + threadIdx.x;
    if (i < n) {
        int pos = atomicAdd(&cur[rows[i]], 1);
        col_s[pos] = cols[i];
    }
}

// ---------------- fused per-hop aggregate + normalize + residual ----------------
// One 64-lane wave per output row. 4 groups x 16 lanes each own one edge slot
// (float4/lane), unrolled x2 -> 8 row-gathers in flight per wave.
// Waves [0, N_ENT) do the entity side, waves [N_ENT, N_ENT+N_USERS) the user side.

__global__ __launch_bounds__(256) void agg_hop(
    const float4* __restrict__ ent_in, const float4* __restrict__ weight4,
    const int* __restrict__ rp_e, const int2* __restrict__ ev,
    float4* __restrict__ ent_out,
    const float4* __restrict__ res_e_in, float4* __restrict__ res_e_out,
    const int* __restrict__ rp_u, const int* __restrict__ col_s,
    const float4* __restrict__ res_u_in, float4* __restrict__ res_u_out) {
    int gwave = (blockIdx.x * blockDim.x + threadIdx.x) >> 6;
    int lane = threadIdx.x & 63;
    int grp = lane >> 4;   // edge slot 0..3
    int sub = lane & 15;   // float4 index within row

    float ax = 0.f, ay = 0.f, az = 0.f, aw = 0.f;

    if (gwave < N_ENT) {
        int row_id = gwave;
        int beg = rp_e[row_id], end = rp_e[row_id + 1];
        for (int p0 = beg; p0 < end; p0 += 8) {
            int peA = p0 + grp;
            int peB = p0 + 4 + grp;
            int2 eA = (peA < end) ? ev[peA] : make_int2(0, 0);
            int2 eB = (peB < end) ? ev[peB] : make_int2(0, 0);
            {
                int t = eA.x & 0xFFFFF, rt = (eA.x >> 20) & 15;
                float sc = __int_as_float(eA.y);
                float4 row = ent_in[(size_t)t * 16 + sub];
                float4 rel = weight4[rt * 16 + sub];
                ax = fmaf(row.x * sc, rel.x, ax);
                ay = fmaf(row.y * sc, rel.y, ay);
                az = fmaf(row.z * sc, rel.z, az);
                aw = fmaf(row.w * sc, rel.w, aw);
            }
            {
                int t = eB.x & 0xFFFFF, rt = (eB.x >> 20) & 15;
                float sc = __int_as_float(eB.y);
                float4 row = ent_in[(size_t)t * 16 + sub];
                float4 rel = weight4[rt * 16 + sub];
                ax = fmaf(row.x * sc, rel.x, ax);
                ay = fmaf(row.y * sc, rel.y, ay);
                az = fmaf(row.z * sc, rel.z, az);
                aw = fmaf(row.w * sc, rel.w, aw);
            }
        }
#pragma unroll
        for (int o = 16; o < 64; o <<= 1) {
            ax += __shfl_xor(ax, o, 64);
            ay += __shfl_xor(ay, o, 64);
            az += __shfl_xor(az, o, 64);
            aw += __shfl_xor(aw, o, 64);
        }
        float ss = ax * ax + ay * ay + az * az + aw * aw;
#pragma unroll
        for (int o = 1; o < 16; o <<= 1) ss += __shfl_xor(ss, o, 64);
        float inv = 1.0f / fmaxf(sqrtf(ss), 1e-12f);
        if (lane < 16) {
            size_t idx = (size_t)row_id * 16 + sub;
            float4 o4 = { ax * inv, ay * inv, az * inv, aw * inv };
            ent_out[idx] = o4;
            float4 r = res_e_in[idx];
            r.x += o4.x; r.y += o4.y; r.z += o4.z; r.w += o4.w;
            res_e_out[idx] = r;
        }
    } else if (gwave < N_ENT + N_USERS) {
        int row_id = gwave - N_ENT;
        int beg = rp_u[row_id], end = rp_u[row_id + 1];
        for (int p0 = beg; p0 < end; p0 += 8) {
            int peA = p0 + grp;
            int peB = p0 + 4 + grp;
            int cA = 0, cB = 0;
            float mA = 0.f, mB = 0.f;
            if (peA < end) { cA = col_s[peA]; mA = 1.f; }
            if (peB < end) { cB = col_s[peB]; mB = 1.f; }
            {
                float4 row = ent_in[(size_t)cA * 16 + sub];
                ax = fmaf(row.x, mA, ax);
                ay = fmaf(row.y, mA, ay);
                az = fmaf(row.z, mA, az);
                aw = fmaf(row.w, mA, aw);
            }
            {
                float4 row = ent_in[(size_t)cB * 16 + sub];
                ax = fmaf(row.x, mB, ax);
                ay = fmaf(row.y, mB, ay);
                az = fmaf(row.z, mB, az);
                aw = fmaf(row.w, mB, aw);
            }
        }
#pragma unroll
        for (int o = 16; o < 64; o <<= 1) {
            ax += __shfl_xor(ax, o, 64);
            ay += __shfl_xor(ay, o, 64);
            az += __shfl_xor(az, o, 64);
            aw += __shfl_xor(aw, o, 64);
        }
        float ss = ax * ax + ay * ay + az * az + aw * aw;
#pragma unroll
        for (int o = 1; o < 16; o <<= 1) ss += __shfl_xor(ss, o, 64);
        float inv = 1.0f / fmaxf(sqrtf(ss), 1e-12f);
        if (lane < 16) {
            size_t idx = (size_t)row_id * 16 + sub;
            float4 r = res_u_in[idx];
            r.x = fmaf(ax, inv, r.x);
            r.y = fmaf(ay, inv, r.y);
            r.z = fmaf(az, inv, r.z);
            r.w = fmaf(aw, inv, r.w);
            res_u_out[idx] = r;
        }
    }
}

// ---------------- launch ----------------

extern "C" void kernel_launch(void* const* d_in, const int* in_sizes, int n_in,
                              void* d_out, int out_size, void* d_ws, size_t ws_size,
                              hipStream_t stream) {
    const float* user_emb   = (const float*)d_in[0];
    const float* entity_emb = (const float*)d_in[1];
    const float* weight     = (const float*)d_in[2];
    const float* unmask     = (const float*)d_in[3];
    const int*   edge_index = (const int*)d_in[4];
    const int*   edge_type  = (const int*)d_in[5];
    const int*   irows      = (const int*)d_in[6];
    const int*   icols      = (const int*)d_in[7];
    const int* head = edge_index;            // edge_index[0]
    const int* tail = edge_index + N_EDGES;  // edge_index[1]

    char* ws = (char*)d_ws;
    size_t off = 0;
    auto alloc = [&](size_t bytes) -> void* {
        void* p = ws + off;
        off += (bytes + 255) & ~(size_t)255;
        return p;
    };
    float* ent_a = (float*)alloc((size_t)N_ENT * DIM * 4);
    float* ent_b = (float*)alloc((size_t)N_ENT * DIM * 4);
    int*   rp_e  = (int*)alloc((N_ENT + 1) * 4);
    int*   cur_e = (int*)alloc(N_ENT * 4);          // counts, then cursor
    int2*  ev    = (int2*)alloc((size_t)N_EDGES * 8);
    int*   rp_u  = (int*)alloc((N_USERS + 1) * 4);
    int*   cur_u = (int*)alloc(N_USERS * 4);
    int*   col_s = (int*)alloc((size_t)NNZ * 4);
    int*   bs_e  = (int*)alloc(1024 * 4);
    int*   bs_u  = (int*)alloc(1024 * 4);
    (void)ws_size;

    // --- CSR build (same every call; deterministic up to f32 sum order) ---
    hipMemsetAsync(cur_e, 0, N_ENT * 4, stream);
    hipMemsetAsync(cur_u, 0, N_USERS * 4, stream);
    hist_kernel<<<2048, 256, 0, stream>>>(head, N_EDGES, cur_e);
    hist_kernel<<<1024, 256, 0, stream>>>(irows, NNZ, cur_u);

    int nb_e = (N_ENT + 255) / 256;    // 391
    int nb_u = (N_USERS + 255) / 256;  // 196
    scan_partial<<<nb_e, 256, 0, stream>>>(cur_e, N_ENT, bs_e);
    scan_bsum<<<1, 1024, 0, stream>>>(bs_e, nb_e);
    scan_final<<<nb_e, 256, 0, stream>>>(cur_e, N_ENT, bs_e, rp_e, cur_e);
    scan_partial<<<nb_u, 256, 0, stream>>>(cur_u, N_USERS, bs_u);
    scan_bsum<<<1, 1024, 0, stream>>>(bs_u, nb_u);
    scan_final<<<nb_u, 256, 0, stream>>>(cur_u, N_USERS, bs_u, rp_u, cur_u);

    scatter_edges<<<(N_EDGES + 255) / 256, 256, 0, stream>>>(
        head, tail, edge_type, unmask, N_EDGES, cur_e, ev);
    scatter_cols<<<(NNZ + 255) / 256, 256, 0, stream>>>(
        irows, icols, NNZ, cur_u, col_s);

    // --- 3 hops (residual init fused into hop 0) ---
    float* res_e = (float*)d_out;
    float* res_u = res_e + (size_t)N_ENT * DIM;
    const float* ent_in = entity_emb;
    float* bufs[2] = {ent_a, ent_b};
    int total_waves = N_ENT + N_USERS;
    int grid = (total_waves + 3) / 4;   // 4 waves / 256-thread block
    for (int h = 0; h < N_HOPS; ++h) {
        float* ent_out = bufs[h & 1];
        const float* re_in = (h == 0) ? entity_emb : res_e;
        const float* ru_in = (h == 0) ? user_emb   : res_u;
        agg_hop<<<grid, 256, 0, stream>>>(
            (const float4*)ent_in, (const float4*)weight,
            rp_e, ev, (float4*)ent_out,
            (const float4*)re_in, (float4*)res_e,
            rp_u, col_s,
            (const float4*)ru_in, (float4*)res_u);
        ent_in = ent_out;
    }
}

// Round 4
// 449.754 us; speedup vs baseline: 2.6889x; 1.5426x over previous
//
#include <hip/hip_runtime.h>
#include <hip/hip_fp16.h>
#include <math.h>

#define N_USERS   50000
#define N_ENT     100000
#define N_EDGES   2000000
#define NNZ       1000000
#define DIM       64
#define N_HOPS    3

// ---------------- helpers ----------------

__device__ inline unsigned pack_h2(float x, float y) {
    unsigned lo = __half_as_ushort(__float2half_rn(x));
    unsigned hi = __half_as_ushort(__float2half_rn(y));
    return lo | (hi << 16);
}

__device__ inline float2 unpack_h2(unsigned u) {
    __half2 h = *reinterpret_cast<__half2*>(&u);
    return __half22float2(h);
}

// f32 -> packed fp16 (uint4 = 8 halves from 2 float4)
__global__ void f32_to_f16(const float4* __restrict__ in, uint4* __restrict__ out, int n4) {
    int i = blockIdx.x * blockDim.x + threadIdx.x;
    if (i < n4) {
        float4 a = in[2 * i], b = in[2 * i + 1];
        uint4 o;
        o.x = pack_h2(a.x, a.y);
        o.y = pack_h2(a.z, a.w);
        o.z = pack_h2(b.x, b.y);
        o.w = pack_h2(b.z, b.w);
        out[i] = o;
    }
}

// ---------------- CSR build ----------------

// histogram + per-edge rank within its segment (rank = old count)
__global__ void hist_rank(const int* __restrict__ key, int n,
                          int* __restrict__ cnt, int* __restrict__ rank) {
    int i = blockIdx.x * blockDim.x + threadIdx.x;
    if (i < n) rank[i] = atomicAdd(&cnt[key[i]], 1);
}

__global__ void scan_partial(const int* __restrict__ cnt, int n, int* __restrict__ bsum) {
    __shared__ int sd[256];
    int tid = threadIdx.x, i = blockIdx.x * 256 + tid;
    sd[tid] = (i < n) ? cnt[i] : 0;
    __syncthreads();
    for (int s = 128; s > 0; s >>= 1) {
        if (tid < s) sd[tid] += sd[tid + s];
        __syncthreads();
    }
    if (tid == 0) bsum[blockIdx.x] = sd[0];
}

// single block, exclusive scan of up to 1024 block sums (in place)
__global__ void scan_bsum(int* bsum, int nb) {
    __shared__ int sd[1024];
    int tid = threadIdx.x;
    int v = (tid < nb) ? bsum[tid] : 0;
    sd[tid] = v;
    __syncthreads();
    for (int o = 1; o < 1024; o <<= 1) {
        int t = (tid >= o) ? sd[tid - o] : 0;
        __syncthreads();
        sd[tid] += t;
        __syncthreads();
    }
    if (tid < nb) bsum[tid] = sd[tid] - v;  // exclusive
}

__global__ void scan_final(const int* __restrict__ cnt, int n,
                           const int* __restrict__ bsum, int* __restrict__ rp) {
    __shared__ int sd[256];
    int tid = threadIdx.x, i = blockIdx.x * 256 + tid;
    int v = (i < n) ? cnt[i] : 0;
    sd[tid] = v;
    __syncthreads();
    for (int o = 1; o < 256; o <<= 1) {
        int t = (tid >= o) ? sd[tid - o] : 0;
        __syncthreads();
        sd[tid] += t;
        __syncthreads();
    }
    int incl = sd[tid] + bsum[blockIdx.x];
    if (i < n) rp[i] = incl - v;       // exclusive prefix
    if (i == n - 1) rp[n] = incl;      // total
}

// atomic-free scatter: pos = rp[key] + rank
__global__ void scatter_edges(const int* __restrict__ head, const int* __restrict__ tail,
                              const int* __restrict__ etype, const float* __restrict__ unmask,
                              int n, const int* __restrict__ rp, const int* __restrict__ rank,
                              int2* __restrict__ ev) {
    int i = blockIdx.x * blockDim.x + threadIdx.x;
    if (i < n) {
        int pos = rp[head[i]] + rank[i];
        ev[pos] = make_int2(tail[i] | ((etype[i] - 1) << 20), __float_as_int(unmask[i]));
    }
}

__global__ void scatter_cols(const int* __restrict__ rows, const int* __restrict__ cols,
                             int n, const int* __restrict__ rp, const int* __restrict__ rank,
                             int* __restrict__ col_s) {
    int i = blockIdx.x * blockDim.x + threadIdx.x;
    if (i < n) {
        int pos = rp[rows[i]] + rank[i];
        col_s[pos] = cols[i];
    }
}

// ---------------- fused per-hop aggregate + normalize + residual ----------------
// One 64-lane wave per output row. fp16 rows (128B): 8 lanes x uint4 per row.
// 8 groups of 8 lanes each own one edge slot, unrolled x2 -> 16 gathers in
// flight per wave. Accumulate f32; normalize + residual (f32) fused.
// Waves [0, N_ENT) entity side, [N_ENT, N_ENT+N_USERS) user side.

__global__ __launch_bounds__(256) void agg_hop(
    const uint4* __restrict__ ent_in16, const uint4* __restrict__ w16,
    const int* __restrict__ rp_e, const int2* __restrict__ ev,
    uint4* __restrict__ ent_out16,
    const float4* __restrict__ res_e_in, float4* __restrict__ res_e_out,
    const int* __restrict__ rp_u, const int* __restrict__ col_s,
    const float4* __restrict__ res_u_in, float4* __restrict__ res_u_out) {
    int gwave = (blockIdx.x * blockDim.x + threadIdx.x) >> 6;
    int lane = threadIdx.x & 63;
    int grp = lane >> 3;   // edge slot 0..7
    int sub = lane & 7;    // uint4 index within fp16 row

    float acc[8];
#pragma unroll
    for (int j = 0; j < 8; ++j) acc[j] = 0.f;

    if (gwave < N_ENT) {
        int row_id = gwave;
        int beg = rp_e[row_id], end = rp_e[row_id + 1];
        for (int p0 = beg; p0 < end; p0 += 16) {
            int peA = p0 + grp;
            int peB = p0 + 8 + grp;
            int2 eA = (peA < end) ? ev[peA] : make_int2(0, 0);
            int2 eB = (peB < end) ? ev[peB] : make_int2(0, 0);
            {
                int t = eA.x & 0xFFFFF, rt = (eA.x >> 20) & 15;
                float sc = __int_as_float(eA.y);
                uint4 r4 = ent_in16[(size_t)t * 8 + sub];
                uint4 w4 = w16[rt * 8 + sub];
                float2 r0 = unpack_h2(r4.x), w0 = unpack_h2(w4.x);
                float2 r1 = unpack_h2(r4.y), w1 = unpack_h2(w4.y);
                float2 r2 = unpack_h2(r4.z), w2 = unpack_h2(w4.z);
                float2 r3 = unpack_h2(r4.w), w3 = unpack_h2(w4.w);
                acc[0] = fmaf(r0.x * sc, w0.x, acc[0]);
                acc[1] = fmaf(r0.y * sc, w0.y, acc[1]);
                acc[2] = fmaf(r1.x * sc, w1.x, acc[2]);
                acc[3] = fmaf(r1.y * sc, w1.y, acc[3]);
                acc[4] = fmaf(r2.x * sc, w2.x, acc[4]);
                acc[5] = fmaf(r2.y * sc, w2.y, acc[5]);
                acc[6] = fmaf(r3.x * sc, w3.x, acc[6]);
                acc[7] = fmaf(r3.y * sc, w3.y, acc[7]);
            }
            {
                int t = eB.x & 0xFFFFF, rt = (eB.x >> 20) & 15;
                float sc = __int_as_float(eB.y);
                uint4 r4 = ent_in16[(size_t)t * 8 + sub];
                uint4 w4 = w16[rt * 8 + sub];
                float2 r0 = unpack_h2(r4.x), w0 = unpack_h2(w4.x);
                float2 r1 = unpack_h2(r4.y), w1 = unpack_h2(w4.y);
                float2 r2 = unpack_h2(r4.z), w2 = unpack_h2(w4.z);
                float2 r3 = unpack_h2(r4.w), w3 = unpack_h2(w4.w);
                acc[0] = fmaf(r0.x * sc, w0.x, acc[0]);
                acc[1] = fmaf(r0.y * sc, w0.y, acc[1]);
                acc[2] = fmaf(r1.x * sc, w1.x, acc[2]);
                acc[3] = fmaf(r1.y * sc, w1.y, acc[3]);
                acc[4] = fmaf(r2.x * sc, w2.x, acc[4]);
                acc[5] = fmaf(r2.y * sc, w2.y, acc[5]);
                acc[6] = fmaf(r3.x * sc, w3.x, acc[6]);
                acc[7] = fmaf(r3.y * sc, w3.y, acc[7]);
            }
        }
#pragma unroll
        for (int o = 8; o < 64; o <<= 1)
#pragma unroll
            for (int j = 0; j < 8; ++j) acc[j] += __shfl_xor(acc[j], o, 64);
        float ss = 0.f;
#pragma unroll
        for (int j = 0; j < 8; ++j) ss = fmaf(acc[j], acc[j], ss);
#pragma unroll
        for (int o = 1; o < 8; o <<= 1) ss += __shfl_xor(ss, o, 64);
        float inv = 1.0f / fmaxf(sqrtf(ss), 1e-12f);
        if (lane < 8) {
            float o0 = acc[0] * inv, o1 = acc[1] * inv, o2 = acc[2] * inv, o3 = acc[3] * inv;
            float o4 = acc[4] * inv, o5 = acc[5] * inv, o6 = acc[6] * inv, o7 = acc[7] * inv;
            uint4 p;
            p.x = pack_h2(o0, o1); p.y = pack_h2(o2, o3);
            p.z = pack_h2(o4, o5); p.w = pack_h2(o6, o7);
            ent_out16[(size_t)row_id * 8 + sub] = p;
            size_t rbase = (size_t)row_id * 16 + sub * 2;
            float4 a = res_e_in[rbase], b = res_e_in[rbase + 1];
            a.x += o0; a.y += o1; a.z += o2; a.w += o3;
            b.x += o4; b.y += o5; b.z += o6; b.w += o7;
            res_e_out[rbase] = a;
            res_e_out[rbase + 1] = b;
        }
    } else if (gwave < N_ENT + N_USERS) {
        int row_id = gwave - N_ENT;
        int beg = rp_u[row_id], end = rp_u[row_id + 1];
        for (int p0 = beg; p0 < end; p0 += 16) {
            int peA = p0 + grp;
            int peB = p0 + 8 + grp;
            int cA = 0, cB = 0;
            float mA = 0.f, mB = 0.f;
            if (peA < end) { cA = col_s[peA]; mA = 1.f; }
            if (peB < end) { cB = col_s[peB]; mB = 1.f; }
            {
                uint4 r4 = ent_in16[(size_t)cA * 8 + sub];
                float2 r0 = unpack_h2(r4.x), r1 = unpack_h2(r4.y);
                float2 r2 = unpack_h2(r4.z), r3 = unpack_h2(r4.w);
                acc[0] = fmaf(r0.x, mA, acc[0]);
                acc[1] = fmaf(r0.y, mA, acc[1]);
                acc[2] = fmaf(r1.x, mA, acc[2]);
                acc[3] = fmaf(r1.y, mA, acc[3]);
                acc[4] = fmaf(r2.x, mA, acc[4]);
                acc[5] = fmaf(r2.y, mA, acc[5]);
                acc[6] = fmaf(r3.x, mA, acc[6]);
                acc[7] = fmaf(r3.y, mA, acc[7]);
            }
            {
                uint4 r4 = ent_in16[(size_t)cB * 8 + sub];
                float2 r0 = unpack_h2(r4.x), r1 = unpack_h2(r4.y);
                float2 r2 = unpack_h2(r4.z), r3 = unpack_h2(r4.w);
                acc[0] = fmaf(r0.x, mB, acc[0]);
                acc[1] = fmaf(r0.y, mB, acc[1]);
                acc[2] = fmaf(r1.x, mB, acc[2]);
                acc[3] = fmaf(r1.y, mB, acc[3]);
                acc[4] = fmaf(r2.x, mB, acc[4]);
                acc[5] = fmaf(r2.y, mB, acc[5]);
                acc[6] = fmaf(r3.x, mB, acc[6]);
                acc[7] = fmaf(r3.y, mB, acc[7]);
            }
        }
#pragma unroll
        for (int o = 8; o < 64; o <<= 1)
#pragma unroll
            for (int j = 0; j < 8; ++j) acc[j] += __shfl_xor(acc[j], o, 64);
        float ss = 0.f;
#pragma unroll
        for (int j = 0; j < 8; ++j) ss = fmaf(acc[j], acc[j], ss);
#pragma unroll
        for (int o = 1; o < 8; o <<= 1) ss += __shfl_xor(ss, o, 64);
        float inv = 1.0f / fmaxf(sqrtf(ss), 1e-12f);
        if (lane < 8) {
            size_t rbase = (size_t)row_id * 16 + sub * 2;
            float4 a = res_u_in[rbase], b = res_u_in[rbase + 1];
            a.x = fmaf(acc[0], inv, a.x); a.y = fmaf(acc[1], inv, a.y);
            a.z = fmaf(acc[2], inv, a.z); a.w = fmaf(acc[3], inv, a.w);
            b.x = fmaf(acc[4], inv, b.x); b.y = fmaf(acc[5], inv, b.y);
            b.z = fmaf(acc[6], inv, b.z); b.w = fmaf(acc[7], inv, b.w);
            res_u_out[rbase] = a;
            res_u_out[rbase + 1] = b;
        }
    }
}

// ---------------- launch ----------------

extern "C" void kernel_launch(void* const* d_in, const int* in_sizes, int n_in,
                              void* d_out, int out_size, void* d_ws, size_t ws_size,
                              hipStream_t stream) {
    const float* user_emb   = (const float*)d_in[0];
    const float* entity_emb = (const float*)d_in[1];
    const float* weight     = (const float*)d_in[2];
    const float* unmask     = (const float*)d_in[3];
    const int*   edge_index = (const int*)d_in[4];
    const int*   edge_type  = (const int*)d_in[5];
    const int*   irows      = (const int*)d_in[6];
    const int*   icols      = (const int*)d_in[7];
    const int* head = edge_index;            // edge_index[0]
    const int* tail = edge_index + N_EDGES;  // edge_index[1]

    char* ws = (char*)d_ws;
    size_t off = 0;
    auto alloc = [&](size_t bytes) -> void* {
        void* p = ws + off;
        off += (bytes + 255) & ~(size_t)255;
        return p;
    };
    uint4* ent16_a = (uint4*)alloc((size_t)N_ENT * DIM * 2);   // 12.8 MB
    uint4* ent16_b = (uint4*)alloc((size_t)N_ENT * DIM * 2);
    uint4* w16     = (uint4*)alloc(16 * DIM * 2);
    int*   rp_e    = (int*)alloc((N_ENT + 1) * 4);
    int*   cnt_e   = (int*)alloc(N_ENT * 4);
    int*   rank_e  = (int*)alloc((size_t)N_EDGES * 4);
    int2*  ev      = (int2*)alloc((size_t)N_EDGES * 8);
    int*   rp_u    = (int*)alloc((N_USERS + 1) * 4);
    int*   cnt_u   = (int*)alloc(N_USERS * 4);
    int*   rank_u  = (int*)alloc((size_t)NNZ * 4);
    int*   col_s   = (int*)alloc((size_t)NNZ * 4);
    int*   bs_e    = (int*)alloc(1024 * 4);
    int*   bs_u    = (int*)alloc(1024 * 4);
    (void)ws_size;

    // --- fp16 conversions (independent of CSR build) ---
    f32_to_f16<<<(N_ENT * DIM / 8 + 255) / 256, 256, 0, stream>>>(
        (const float4*)entity_emb, ent16_a, N_ENT * DIM / 8);
    f32_to_f16<<<1, 128, 0, stream>>>((const float4*)weight, w16, 16 * DIM / 8);

    // --- CSR build ---
    hipMemsetAsync(cnt_e, 0, N_ENT * 4, stream);
    hipMemsetAsync(cnt_u, 0, N_USERS * 4, stream);
    hist_rank<<<(N_EDGES + 255) / 256, 256, 0, stream>>>(head, N_EDGES, cnt_e, rank_e);
    hist_rank<<<(NNZ + 255) / 256, 256, 0, stream>>>(irows, NNZ, cnt_u, rank_u);

    int nb_e = (N_ENT + 255) / 256;    // 391
    int nb_u = (N_USERS + 255) / 256;  // 196
    scan_partial<<<nb_e, 256, 0, stream>>>(cnt_e, N_ENT, bs_e);
    scan_bsum<<<1, 1024, 0, stream>>>(bs_e, nb_e);
    scan_final<<<nb_e, 256, 0, stream>>>(cnt_e, N_ENT, bs_e, rp_e);
    scan_partial<<<nb_u, 256, 0, stream>>>(cnt_u, N_USERS, bs_u);
    scan_bsum<<<1, 1024, 0, stream>>>(bs_u, nb_u);
    scan_final<<<nb_u, 256, 0, stream>>>(cnt_u, N_USERS, bs_u, rp_u);

    scatter_edges<<<(N_EDGES + 255) / 256, 256, 0, stream>>>(
        head, tail, edge_type, unmask, N_EDGES, rp_e, rank_e, ev);
    scatter_cols<<<(NNZ + 255) / 256, 256, 0, stream>>>(
        irows, icols, NNZ, rp_u, rank_u, col_s);

    // --- 3 hops (residual init fused into hop 0) ---
    float* res_e = (float*)d_out;
    float* res_u = res_e + (size_t)N_ENT * DIM;
    int total_waves = N_ENT + N_USERS;
    int grid = (total_waves + 3) / 4;   // 4 waves / 256-thread block
    const uint4* in16 = ent16_a;
    uint4* out16 = ent16_b;
    for (int h = 0; h < N_HOPS; ++h) {
        const float* re_in = (h == 0) ? entity_emb : res_e;
        const float* ru_in = (h == 0) ? user_emb   : res_u;
        agg_hop<<<grid, 256, 0, stream>>>(
            in16, w16, rp_e, ev, out16,
            (const float4*)re_in, (float4*)res_e,
            rp_u, col_s,
            (const float4*)ru_in, (float4*)res_u);
        uint4* t = out16; out16 = (uint4*)in16; in16 = t;
    }
}

// Round 5
// 443.686 us; speedup vs baseline: 2.7257x; 1.0137x over previous
//
#include <hip/hip_runtime.h>
#include <hip/hip_fp16.h>
#include <math.h>

#define N_USERS   50000
#define N_ENT     100000
#define N_EDGES   2000000
#define NNZ       1000000
#define DIM       64
#define N_HOPS    3
#define HALF_E    (N_ENT / 2)
#define HALF_U    (N_USERS / 2)

// ---------------- helpers ----------------

__device__ inline unsigned pack_h2(float x, float y) {
    unsigned lo = __half_as_ushort(__float2half_rn(x));
    unsigned hi = __half_as_ushort(__float2half_rn(y));
    return lo | (hi << 16);
}

__device__ inline float2 unpack_h2(unsigned u) {
    __half2 h = *reinterpret_cast<__half2*>(&u);
    return __half22float2(h);
}

// f32 -> packed fp16 (uint4 = 8 halves from 2 float4)
__global__ void f32_to_f16(const float4* __restrict__ in, uint4* __restrict__ out, int n4) {
    int i = blockIdx.x * blockDim.x + threadIdx.x;
    if (i < n4) {
        float4 a = in[2 * i], b = in[2 * i + 1];
        uint4 o;
        o.x = pack_h2(a.x, a.y);
        o.y = pack_h2(a.z, a.w);
        o.z = pack_h2(b.x, b.y);
        o.w = pack_h2(b.z, b.w);
        out[i] = o;
    }
}

// ---------------- CSR build ----------------

// merged histogram+rank for both edge sets (latency-bound; overlap their stalls)
__global__ void hist_rank_both(const int* __restrict__ head, const int* __restrict__ irows,
                               int* __restrict__ cnt_e, int* __restrict__ cnt_u,
                               int* __restrict__ rank_e, int* __restrict__ rank_u) {
    int i = blockIdx.x * blockDim.x + threadIdx.x;
    if (i < N_EDGES) {
        rank_e[i] = atomicAdd(&cnt_e[head[i]], 1);
    } else if (i < N_EDGES + NNZ) {
        int j = i - N_EDGES;
        rank_u[j] = atomicAdd(&cnt_u[irows[j]], 1);
    }
}

__global__ void scan_partial(const int* __restrict__ cnt, int n, int* __restrict__ bsum) {
    __shared__ int sd[256];
    int tid = threadIdx.x, i = blockIdx.x * 256 + tid;
    sd[tid] = (i < n) ? cnt[i] : 0;
    __syncthreads();
    for (int s = 128; s > 0; s >>= 1) {
        if (tid < s) sd[tid] += sd[tid + s];
        __syncthreads();
    }
    if (tid == 0) bsum[blockIdx.x] = sd[0];
}

__global__ void scan_bsum(int* bsum, int nb) {
    __shared__ int sd[1024];
    int tid = threadIdx.x;
    int v = (tid < nb) ? bsum[tid] : 0;
    sd[tid] = v;
    __syncthreads();
    for (int o = 1; o < 1024; o <<= 1) {
        int t = (tid >= o) ? sd[tid - o] : 0;
        __syncthreads();
        sd[tid] += t;
        __syncthreads();
    }
    if (tid < nb) bsum[tid] = sd[tid] - v;  // exclusive
}

__global__ void scan_final(const int* __restrict__ cnt, int n,
                           const int* __restrict__ bsum, int* __restrict__ rp) {
    __shared__ int sd[256];
    int tid = threadIdx.x, i = blockIdx.x * 256 + tid;
    int v = (i < n) ? cnt[i] : 0;
    sd[tid] = v;
    __syncthreads();
    for (int o = 1; o < 256; o <<= 1) {
        int t = (tid >= o) ? sd[tid - o] : 0;
        __syncthreads();
        sd[tid] += t;
        __syncthreads();
    }
    int incl = sd[tid] + bsum[blockIdx.x];
    if (i < n) rp[i] = incl - v;
    if (i == n - 1) rp[n] = incl;
}

// merged atomic-free scatter; non-temporal stores to cut cross-XCD line bounce
__global__ void scatter_both(const int* __restrict__ head, const int* __restrict__ tail,
                             const int* __restrict__ etype, const float* __restrict__ unmask,
                             const int* __restrict__ rp_e, const int* __restrict__ rank_e,
                             long long* __restrict__ ev,
                             const int* __restrict__ irows, const int* __restrict__ icols,
                             const int* __restrict__ rp_u, const int* __restrict__ rank_u,
                             int* __restrict__ col_s) {
    int i = blockIdx.x * blockDim.x + threadIdx.x;
    if (i < N_EDGES) {
        int pos = rp_e[head[i]] + rank_e[i];
        unsigned lo = (unsigned)(tail[i] | ((etype[i] - 1) << 20));
        unsigned hi = (unsigned)__float_as_int(unmask[i]);
        long long v = (long long)(((unsigned long long)hi << 32) | lo);
        __builtin_nontemporal_store(v, &ev[pos]);
    } else if (i < N_EDGES + NNZ) {
        int j = i - N_EDGES;
        int pos = rp_u[irows[j]] + rank_u[j];
        __builtin_nontemporal_store(icols[j], &col_s[pos]);
    }
}

// ---------------- fused per-hop aggregate + normalize ----------------
// 2 rows per wave: lanes 0-31 row A, 32-63 row B. Within a 32-half:
// 4 edge slots x 8 lanes (uint4 = 8 fp16 dims per lane), unrolled x2
// -> 8 edges in flight per row per iter. Weight table stays f32 (L1).
// FINAL=0: write fp16 hop output. FINAL=1: fuse res = emb + n1 + n2 + n3.

__device__ inline void edge_body(const uint4* __restrict__ in16,
                                 const float4* __restrict__ w32,
                                 int ex, float sc, int sub, float (&acc)[8]) {
    int t = ex & 0xFFFFF, rt = (ex >> 20) & 15;
    uint4 r4 = in16[(size_t)t * 8 + sub];
    float4 wa = w32[rt * 16 + sub * 2];
    float4 wb = w32[rt * 16 + sub * 2 + 1];
    float2 r0 = unpack_h2(r4.x), r1 = unpack_h2(r4.y);
    float2 r2 = unpack_h2(r4.z), r3 = unpack_h2(r4.w);
    acc[0] = fmaf(r0.x * sc, wa.x, acc[0]);
    acc[1] = fmaf(r0.y * sc, wa.y, acc[1]);
    acc[2] = fmaf(r1.x * sc, wa.z, acc[2]);
    acc[3] = fmaf(r1.y * sc, wa.w, acc[3]);
    acc[4] = fmaf(r2.x * sc, wb.x, acc[4]);
    acc[5] = fmaf(r2.y * sc, wb.y, acc[5]);
    acc[6] = fmaf(r3.x * sc, wb.z, acc[6]);
    acc[7] = fmaf(r3.y * sc, wb.w, acc[7]);
}

template <int FINAL>
__global__ __launch_bounds__(256) void agg_hop(
    const uint4* __restrict__ in16, const float4* __restrict__ w32,
    const int* __restrict__ rp_e, const int2* __restrict__ ev,
    const int* __restrict__ rp_u, const int* __restrict__ col_s,
    uint4* __restrict__ oute, uint4* __restrict__ outu,
    const uint4* __restrict__ pe1, const uint4* __restrict__ pu1,
    const uint4* __restrict__ pu2,
    const float4* __restrict__ emb_e, const float4* __restrict__ emb_u,
    float4* __restrict__ res_e, float4* __restrict__ res_u) {
    int gwave = (blockIdx.x * blockDim.x + threadIdx.x) >> 6;
    if (gwave >= HALF_E + HALF_U) return;
    int lane = threadIdx.x & 63;
    int half = lane >> 5;
    int grp = (lane >> 3) & 3;   // edge slot 0..3 within the 32-half
    int sub = lane & 7;          // uint4 index within fp16 row

    bool is_ent = gwave < HALF_E;
    int row = is_ent ? gwave * 2 + half : (gwave - HALF_E) * 2 + half;
    const int* __restrict__ rp = is_ent ? rp_e : rp_u;
    int beg = rp[row], end = rp[row + 1];

    float acc[8];
#pragma unroll
    for (int j = 0; j < 8; ++j) acc[j] = 0.f;

    if (is_ent) {
        for (int p0 = beg; p0 < end; p0 += 8) {
            int pA = p0 + grp, pB = p0 + 4 + grp;
            int2 eA = (pA < end) ? ev[pA] : make_int2(0, 0);
            int2 eB = (pB < end) ? ev[pB] : make_int2(0, 0);
            edge_body(in16, w32, eA.x, __int_as_float(eA.y), sub, acc);
            edge_body(in16, w32, eB.x, __int_as_float(eB.y), sub, acc);
        }
    } else {
        for (int p0 = beg; p0 < end; p0 += 8) {
            int pA = p0 + grp, pB = p0 + 4 + grp;
            int cA = 0, cB = 0;
            float mA = 0.f, mB = 0.f;
            if (pA < end) { cA = col_s[pA]; mA = 1.f; }
            if (pB < end) { cB = col_s[pB]; mB = 1.f; }
            {
                uint4 r4 = in16[(size_t)cA * 8 + sub];
                float2 r0 = unpack_h2(r4.x), r1 = unpack_h2(r4.y);
                float2 r2 = unpack_h2(r4.z), r3 = unpack_h2(r4.w);
                acc[0] = fmaf(r0.x, mA, acc[0]); acc[1] = fmaf(r0.y, mA, acc[1]);
                acc[2] = fmaf(r1.x, mA, acc[2]); acc[3] = fmaf(r1.y, mA, acc[3]);
                acc[4] = fmaf(r2.x, mA, acc[4]); acc[5] = fmaf(r2.y, mA, acc[5]);
                acc[6] = fmaf(r3.x, mA, acc[6]); acc[7] = fmaf(r3.y, mA, acc[7]);
            }
            {
                uint4 r4 = in16[(size_t)cB * 8 + sub];
                float2 r0 = unpack_h2(r4.x), r1 = unpack_h2(r4.y);
                float2 r2 = unpack_h2(r4.z), r3 = unpack_h2(r4.w);
                acc[0] = fmaf(r0.x, mB, acc[0]); acc[1] = fmaf(r0.y, mB, acc[1]);
                acc[2] = fmaf(r1.x, mB, acc[2]); acc[3] = fmaf(r1.y, mB, acc[3]);
                acc[4] = fmaf(r2.x, mB, acc[4]); acc[5] = fmaf(r2.y, mB, acc[5]);
                acc[6] = fmaf(r3.x, mB, acc[6]); acc[7] = fmaf(r3.y, mB, acc[7]);
            }
        }
    }

    // fold the 4 edge slots (stays within each 32-half: offsets 8, 16)
#pragma unroll
    for (int j = 0; j < 8; ++j) {
        acc[j] += __shfl_xor(acc[j], 8, 64);
        acc[j] += __shfl_xor(acc[j], 16, 64);
    }
    float ss = 0.f;
#pragma unroll
    for (int j = 0; j < 8; ++j) ss = fmaf(acc[j], acc[j], ss);
    ss += __shfl_xor(ss, 1, 64);
    ss += __shfl_xor(ss, 2, 64);
    ss += __shfl_xor(ss, 4, 64);
    float inv = 1.0f / fmaxf(sqrtf(ss), 1e-12f);

    if (grp == 0) {
        float n0 = acc[0] * inv, n1 = acc[1] * inv, n2 = acc[2] * inv, n3 = acc[3] * inv;
        float n4 = acc[4] * inv, n5 = acc[5] * inv, n6 = acc[6] * inv, n7 = acc[7] * inv;
        if constexpr (!FINAL) {
            uint4 p;
            p.x = pack_h2(n0, n1); p.y = pack_h2(n2, n3);
            p.z = pack_h2(n4, n5); p.w = pack_h2(n6, n7);
            (is_ent ? oute : outu)[(size_t)row * 8 + sub] = p;
        } else {
            const uint4* q1p = is_ent ? pe1 : pu1;   // hop-1 output
            const uint4* q2p = is_ent ? in16 : pu2;  // hop-2 output (entity: own input)
            uint4 q1 = q1p[(size_t)row * 8 + sub];
            uint4 q2 = q2p[(size_t)row * 8 + sub];
            const float4* emb = is_ent ? emb_e : emb_u;
            float4* res = is_ent ? res_e : res_u;
            size_t rb = (size_t)row * 16 + sub * 2;
            float4 a = emb[rb], b = emb[rb + 1];
            float2 x0 = unpack_h2(q1.x), x1 = unpack_h2(q1.y);
            float2 x2 = unpack_h2(q1.z), x3 = unpack_h2(q1.w);
            float2 y0 = unpack_h2(q2.x), y1 = unpack_h2(q2.y);
            float2 y2 = unpack_h2(q2.z), y3 = unpack_h2(q2.w);
            a.x += n0 + x0.x + y0.x;  a.y += n1 + x0.y + y0.y;
            a.z += n2 + x1.x + y1.x;  a.w += n3 + x1.y + y1.y;
            b.x += n4 + x2.x + y2.x;  b.y += n5 + x2.y + y2.y;
            b.z += n6 + x3.x + y3.x;  b.w += n7 + x3.y + y3.y;
            res[rb] = a;
            res[rb + 1] = b;
        }
    }
}

// ---------------- launch ----------------

extern "C" void kernel_launch(void* const* d_in, const int* in_sizes, int n_in,
                              void* d_out, int out_size, void* d_ws, size_t ws_size,
                              hipStream_t stream) {
    const float* user_emb   = (const float*)d_in[0];
    const float* entity_emb = (const float*)d_in[1];
    const float* weight     = (const float*)d_in[2];
    const float* unmask     = (const float*)d_in[3];
    const int*   edge_index = (const int*)d_in[4];
    const int*   edge_type  = (const int*)d_in[5];
    const int*   irows      = (const int*)d_in[6];
    const int*   icols      = (const int*)d_in[7];
    const int* head = edge_index;            // edge_index[0]
    const int* tail = edge_index + N_EDGES;  // edge_index[1]

    char* ws = (char*)d_ws;
    size_t off = 0;
    auto alloc = [&](size_t bytes) -> void* {
        void* p = ws + off;
        off += (bytes + 255) & ~(size_t)255;
        return p;
    };
    uint4* B0     = (uint4*)alloc((size_t)N_ENT * DIM * 2);   // fp16 emb
    uint4* B1     = (uint4*)alloc((size_t)N_ENT * DIM * 2);   // n1 (ent)
    uint4* B2     = (uint4*)alloc((size_t)N_ENT * DIM * 2);   // n2 (ent)
    uint4* U1     = (uint4*)alloc((size_t)N_USERS * DIM * 2); // n1 (usr)
    uint4* U2     = (uint4*)alloc((size_t)N_USERS * DIM * 2); // n2 (usr)
    int*   rp_e   = (int*)alloc((N_ENT + 1) * 4);
    int*   cnt_e  = (int*)alloc(N_ENT * 4);
    int*   rank_e = (int*)alloc((size_t)N_EDGES * 4);
    int2*  ev     = (int2*)alloc((size_t)N_EDGES * 8);
    int*   rp_u   = (int*)alloc((N_USERS + 1) * 4);
    int*   cnt_u  = (int*)alloc(N_USERS * 4);
    int*   rank_u = (int*)alloc((size_t)NNZ * 4);
    int*   col_s  = (int*)alloc((size_t)NNZ * 4);
    int*   bs_e   = (int*)alloc(1024 * 4);
    int*   bs_u   = (int*)alloc(1024 * 4);
    (void)ws_size;

    // --- fp16 conversion of entity table (independent of CSR build) ---
    f32_to_f16<<<(N_ENT * DIM / 8 + 255) / 256, 256, 0, stream>>>(
        (const float4*)entity_emb, B0, N_ENT * DIM / 8);

    // --- CSR build ---
    hipMemsetAsync(cnt_e, 0, N_ENT * 4, stream);
    hipMemsetAsync(cnt_u, 0, N_USERS * 4, stream);
    hist_rank_both<<<(N_EDGES + NNZ + 255) / 256, 256, 0, stream>>>(
        head, irows, cnt_e, cnt_u, rank_e, rank_u);

    int nb_e = (N_ENT + 255) / 256;    // 391
    int nb_u = (N_USERS + 255) / 256;  // 196
    scan_partial<<<nb_e, 256, 0, stream>>>(cnt_e, N_ENT, bs_e);
    scan_bsum<<<1, 1024, 0, stream>>>(bs_e, nb_e);
    scan_final<<<nb_e, 256, 0, stream>>>(cnt_e, N_ENT, bs_e, rp_e);
    scan_partial<<<nb_u, 256, 0, stream>>>(cnt_u, N_USERS, bs_u);
    scan_bsum<<<1, 1024, 0, stream>>>(bs_u, nb_u);
    scan_final<<<nb_u, 256, 0, stream>>>(cnt_u, N_USERS, bs_u, rp_u);

    scatter_both<<<(N_EDGES + NNZ + 255) / 256, 256, 0, stream>>>(
        head, tail, edge_type, unmask, rp_e, rank_e, (long long*)ev,
        irows, icols, rp_u, rank_u, col_s);

    // --- 3 hops: h0,h1 write fp16 outputs; h2 fuses residual sum ---
    float* res_e = (float*)d_out;
    float* res_u = res_e + (size_t)N_ENT * DIM;
    const float4* w32 = (const float4*)weight;
    int grid_agg = ((HALF_E + HALF_U) * 64 + 255) / 256;

    agg_hop<0><<<grid_agg, 256, 0, stream>>>(
        B0, w32, rp_e, ev, rp_u, col_s, B1, U1,
        nullptr, nullptr, nullptr, nullptr, nullptr, nullptr, nullptr);
    agg_hop<0><<<grid_agg, 256, 0, stream>>>(
        B1, w32, rp_e, ev, rp_u, col_s, B2, U2,
        nullptr, nullptr, nullptr, nullptr, nullptr, nullptr, nullptr);
    agg_hop<1><<<grid_agg, 256, 0, stream>>>(
        B2, w32, rp_e, ev, rp_u, col_s, nullptr, nullptr,
        B1, U1, U2,
        (const float4*)entity_emb, (const float4*)user_emb,
        (float4*)res_e, (float4*)res_u);
}

// Round 6
// 436.535 us; speedup vs baseline: 2.7703x; 1.0164x over previous
//
#include <hip/hip_runtime.h>
#include <hip/hip_fp16.h>
#include <math.h>

#define N_USERS   50000
#define N_ENT     100000
#define N_EDGES   2000000
#define NNZ       1000000
#define DIM       64
#define N_HOPS    3
#define HALF_E    (N_ENT / 2)
#define HALF_U    (N_USERS / 2)
#define NREP      8   // one counter replica per XCD (blockIdx % 8 heuristic)

// ---------------- helpers ----------------

__device__ inline unsigned pack_h2(float x, float y) {
    unsigned lo = __half_as_ushort(__float2half_rn(x));
    unsigned hi = __half_as_ushort(__float2half_rn(y));
    return lo | (hi << 16);
}

__device__ inline float2 unpack_h2(unsigned u) {
    __half2 h = *reinterpret_cast<__half2*>(&u);
    return __half22float2(h);
}

// f32 -> packed fp16 (uint4 = 8 halves from 2 float4)
__global__ void f32_to_f16(const float4* __restrict__ in, uint4* __restrict__ out, int n4) {
    int i = blockIdx.x * blockDim.x + threadIdx.x;
    if (i < n4) {
        float4 a = in[2 * i], b = in[2 * i + 1];
        uint4 o;
        o.x = pack_h2(a.x, a.y);
        o.y = pack_h2(a.z, a.w);
        o.z = pack_h2(b.x, b.y);
        o.w = pack_h2(b.z, b.w);
        out[i] = o;
    }
}

// ---------------- CSR build ----------------
// XCD-replicated histogram: replica = blockIdx & 7 ~ XCD id (round-robin
// dispatch heuristic). Each replica's counter lines are touched by one XCD
// only -> they pin in that XCD's L2 instead of ping-ponging via HBM.

__global__ void hist_rank_both(const int* __restrict__ head, const int* __restrict__ irows,
                               int* __restrict__ cnt_e, int* __restrict__ cnt_u,
                               int* __restrict__ rank_e, int* __restrict__ rank_u) {
    int g = blockIdx.x * 256 + threadIdx.x;
    int rep = blockIdx.x & (NREP - 1);
    if (g < N_EDGES) {
        rank_e[g] = atomicAdd(&cnt_e[rep * N_ENT + head[g]], 1);
    } else if (g < N_EDGES + NNZ) {
        int j = g - N_EDGES;
        rank_u[j] = atomicAdd(&cnt_u[rep * N_USERS + irows[j]], 1);
    }
}

// fold replicas: cnt[r][k] <- exclusive prefix over r (in place); tot[k] = sum
__global__ void replica_fold(int* __restrict__ cnt_e, int* __restrict__ cnt_u,
                             int* __restrict__ tot_e, int* __restrict__ tot_u) {
    int k = blockIdx.x * blockDim.x + threadIdx.x;
    if (k < N_ENT) {
        int s = 0;
#pragma unroll
        for (int r = 0; r < NREP; ++r) {
            int c = cnt_e[r * N_ENT + k];
            cnt_e[r * N_ENT + k] = s;
            s += c;
        }
        tot_e[k] = s;
    } else if (k < N_ENT + N_USERS) {
        int kk = k - N_ENT;
        int s = 0;
#pragma unroll
        for (int r = 0; r < NREP; ++r) {
            int c = cnt_u[r * N_USERS + kk];
            cnt_u[r * N_USERS + kk] = s;
            s += c;
        }
        tot_u[kk] = s;
    }
}

__global__ void scan_partial(const int* __restrict__ cnt, int n, int* __restrict__ bsum) {
    __shared__ int sd[256];
    int tid = threadIdx.x, i = blockIdx.x * 256 + tid;
    sd[tid] = (i < n) ? cnt[i] : 0;
    __syncthreads();
    for (int s = 128; s > 0; s >>= 1) {
        if (tid < s) sd[tid] += sd[tid + s];
        __syncthreads();
    }
    if (tid == 0) bsum[blockIdx.x] = sd[0];
}

__global__ void scan_bsum(int* bsum, int nb) {
    __shared__ int sd[1024];
    int tid = threadIdx.x;
    int v = (tid < nb) ? bsum[tid] : 0;
    sd[tid] = v;
    __syncthreads();
    for (int o = 1; o < 1024; o <<= 1) {
        int t = (tid >= o) ? sd[tid - o] : 0;
        __syncthreads();
        sd[tid] += t;
        __syncthreads();
    }
    if (tid < nb) bsum[tid] = sd[tid] - v;  // exclusive
}

__global__ void scan_final(const int* __restrict__ cnt, int n,
                           const int* __restrict__ bsum, int* __restrict__ rp) {
    __shared__ int sd[256];
    int tid = threadIdx.x, i = blockIdx.x * 256 + tid;
    int v = (i < n) ? cnt[i] : 0;
    sd[tid] = v;
    __syncthreads();
    for (int o = 1; o < 256; o <<= 1) {
        int t = (tid >= o) ? sd[tid - o] : 0;
        __syncthreads();
        sd[tid] += t;
        __syncthreads();
    }
    int incl = sd[tid] + bsum[blockIdx.x];
    if (i < n) rp[i] = incl - v;
    if (i == n - 1) rp[n] = incl;
}

// atomic-free scatter: pos = rp[key] + replica_off[rep][key] + local rank.
// rep recomputed from the SAME grid mapping as hist_rank_both.
__global__ void scatter_both(const int* __restrict__ head, const int* __restrict__ tail,
                             const int* __restrict__ etype, const float* __restrict__ unmask,
                             const int* __restrict__ rp_e, const int* __restrict__ off_e,
                             const int* __restrict__ rank_e, long long* __restrict__ ev,
                             const int* __restrict__ irows, const int* __restrict__ icols,
                             const int* __restrict__ rp_u, const int* __restrict__ off_u,
                             const int* __restrict__ rank_u, int* __restrict__ col_s) {
    int g = blockIdx.x * 256 + threadIdx.x;
    int rep = blockIdx.x & (NREP - 1);
    if (g < N_EDGES) {
        int k = head[g];
        int pos = rp_e[k] + off_e[rep * N_ENT + k] + rank_e[g];
        unsigned lo = (unsigned)(tail[g] | ((etype[g] - 1) << 20));
        unsigned hi = (unsigned)__float_as_int(unmask[g]);
        long long v = (long long)(((unsigned long long)hi << 32) | lo);
        __builtin_nontemporal_store(v, &ev[pos]);
    } else if (g < N_EDGES + NNZ) {
        int j = g - N_EDGES;
        int k = irows[j];
        int pos = rp_u[k] + off_u[rep * N_USERS + k] + rank_u[j];
        __builtin_nontemporal_store(icols[j], &col_s[pos]);
    }
}

// ---------------- fused per-hop aggregate + normalize ----------------
// 2 rows per wave: lanes 0-31 row A, 32-63 row B. Within a 32-half:
// 4 edge slots x 8 lanes (uint4 = 8 fp16 dims per lane), unrolled x2
// -> 8 edges in flight per row per iter. Weight table stays f32 (L1).
// FINAL=0: write fp16 hop output. FINAL=1: fuse res = emb + n1 + n2 + n3.

__device__ inline void edge_body(const uint4* __restrict__ in16,
                                 const float4* __restrict__ w32,
                                 int ex, float sc, int sub, float (&acc)[8]) {
    int t = ex & 0xFFFFF, rt = (ex >> 20) & 15;
    uint4 r4 = in16[(size_t)t * 8 + sub];
    float4 wa = w32[rt * 16 + sub * 2];
    float4 wb = w32[rt * 16 + sub * 2 + 1];
    float2 r0 = unpack_h2(r4.x), r1 = unpack_h2(r4.y);
    float2 r2 = unpack_h2(r4.z), r3 = unpack_h2(r4.w);
    acc[0] = fmaf(r0.x * sc, wa.x, acc[0]);
    acc[1] = fmaf(r0.y * sc, wa.y, acc[1]);
    acc[2] = fmaf(r1.x * sc, wa.z, acc[2]);
    acc[3] = fmaf(r1.y * sc, wa.w, acc[3]);
    acc[4] = fmaf(r2.x * sc, wb.x, acc[4]);
    acc[5] = fmaf(r2.y * sc, wb.y, acc[5]);
    acc[6] = fmaf(r3.x * sc, wb.z, acc[6]);
    acc[7] = fmaf(r3.y * sc, wb.w, acc[7]);
}

template <int FINAL>
__global__ __launch_bounds__(256) void agg_hop(
    const uint4* __restrict__ in16, const float4* __restrict__ w32,
    const int* __restrict__ rp_e, const int2* __restrict__ ev,
    const int* __restrict__ rp_u, const int* __restrict__ col_s,
    uint4* __restrict__ oute, uint4* __restrict__ outu,
    const uint4* __restrict__ pe1, const uint4* __restrict__ pu1,
    const uint4* __restrict__ pu2,
    const float4* __restrict__ emb_e, const float4* __restrict__ emb_u,
    float4* __restrict__ res_e, float4* __restrict__ res_u) {
    int gwave = (blockIdx.x * blockDim.x + threadIdx.x) >> 6;
    if (gwave >= HALF_E + HALF_U) return;
    int lane = threadIdx.x & 63;
    int half = lane >> 5;
    int grp = (lane >> 3) & 3;   // edge slot 0..3 within the 32-half
    int sub = lane & 7;          // uint4 index within fp16 row

    bool is_ent = gwave < HALF_E;
    int row = is_ent ? gwave * 2 + half : (gwave - HALF_E) * 2 + half;
    const int* __restrict__ rp = is_ent ? rp_e : rp_u;
    int beg = rp[row], end = rp[row + 1];

    float acc[8];
#pragma unroll
    for (int j = 0; j < 8; ++j) acc[j] = 0.f;

    if (is_ent) {
        for (int p0 = beg; p0 < end; p0 += 8) {
            int pA = p0 + grp, pB = p0 + 4 + grp;
            int2 eA = (pA < end) ? ev[pA] : make_int2(0, 0);
            int2 eB = (pB < end) ? ev[pB] : make_int2(0, 0);
            edge_body(in16, w32, eA.x, __int_as_float(eA.y), sub, acc);
            edge_body(in16, w32, eB.x, __int_as_float(eB.y), sub, acc);
        }
    } else {
        for (int p0 = beg; p0 < end; p0 += 8) {
            int pA = p0 + grp, pB = p0 + 4 + grp;
            int cA = 0, cB = 0;
            float mA = 0.f, mB = 0.f;
            if (pA < end) { cA = col_s[pA]; mA = 1.f; }
            if (pB < end) { cB = col_s[pB]; mB = 1.f; }
            {
                uint4 r4 = in16[(size_t)cA * 8 + sub];
                float2 r0 = unpack_h2(r4.x), r1 = unpack_h2(r4.y);
                float2 r2 = unpack_h2(r4.z), r3 = unpack_h2(r4.w);
                acc[0] = fmaf(r0.x, mA, acc[0]); acc[1] = fmaf(r0.y, mA, acc[1]);
                acc[2] = fmaf(r1.x, mA, acc[2]); acc[3] = fmaf(r1.y, mA, acc[3]);
                acc[4] = fmaf(r2.x, mA, acc[4]); acc[5] = fmaf(r2.y, mA, acc[5]);
                acc[6] = fmaf(r3.x, mA, acc[6]); acc[7] = fmaf(r3.y, mA, acc[7]);
            }
            {
                uint4 r4 = in16[(size_t)cB * 8 + sub];
                float2 r0 = unpack_h2(r4.x), r1 = unpack_h2(r4.y);
                float2 r2 = unpack_h2(r4.z), r3 = unpack_h2(r4.w);
                acc[0] = fmaf(r0.x, mB, acc[0]); acc[1] = fmaf(r0.y, mB, acc[1]);
                acc[2] = fmaf(r1.x, mB, acc[2]); acc[3] = fmaf(r1.y, mB, acc[3]);
                acc[4] = fmaf(r2.x, mB, acc[4]); acc[5] = fmaf(r2.y, mB, acc[5]);
                acc[6] = fmaf(r3.x, mB, acc[6]); acc[7] = fmaf(r3.y, mB, acc[7]);
            }
        }
    }

    // fold the 4 edge slots (stays within each 32-half: offsets 8, 16)
#pragma unroll
    for (int j = 0; j < 8; ++j) {
        acc[j] += __shfl_xor(acc[j], 8, 64);
        acc[j] += __shfl_xor(acc[j], 16, 64);
    }
    float ss = 0.f;
#pragma unroll
    for (int j = 0; j < 8; ++j) ss = fmaf(acc[j], acc[j], ss);
    ss += __shfl_xor(ss, 1, 64);
    ss += __shfl_xor(ss, 2, 64);
    ss += __shfl_xor(ss, 4, 64);
    float inv = 1.0f / fmaxf(sqrtf(ss), 1e-12f);

    if (grp == 0) {
        float n0 = acc[0] * inv, n1 = acc[1] * inv, n2 = acc[2] * inv, n3 = acc[3] * inv;
        float n4 = acc[4] * inv, n5 = acc[5] * inv, n6 = acc[6] * inv, n7 = acc[7] * inv;
        if constexpr (!FINAL) {
            uint4 p;
            p.x = pack_h2(n0, n1); p.y = pack_h2(n2, n3);
            p.z = pack_h2(n4, n5); p.w = pack_h2(n6, n7);
            (is_ent ? oute : outu)[(size_t)row * 8 + sub] = p;
        } else {
            const uint4* q1p = is_ent ? pe1 : pu1;   // hop-1 output
            const uint4* q2p = is_ent ? in16 : pu2;  // hop-2 output (entity: own input)
            uint4 q1 = q1p[(size_t)row * 8 + sub];
            uint4 q2 = q2p[(size_t)row * 8 + sub];
            const float4* emb = is_ent ? emb_e : emb_u;
            float4* res = is_ent ? res_e : res_u;
            size_t rb = (size_t)row * 16 + sub * 2;
            float4 a = emb[rb], b = emb[rb + 1];
            float2 x0 = unpack_h2(q1.x), x1 = unpack_h2(q1.y);
            float2 x2 = unpack_h2(q1.z), x3 = unpack_h2(q1.w);
            float2 y0 = unpack_h2(q2.x), y1 = unpack_h2(q2.y);
            float2 y2 = unpack_h2(q2.z), y3 = unpack_h2(q2.w);
            a.x += n0 + x0.x + y0.x;  a.y += n1 + x0.y + y0.y;
            a.z += n2 + x1.x + y1.x;  a.w += n3 + x1.y + y1.y;
            b.x += n4 + x2.x + y2.x;  b.y += n5 + x2.y + y2.y;
            b.z += n6 + x3.x + y3.x;  b.w += n7 + x3.y + y3.y;
            res[rb] = a;
            res[rb + 1] = b;
        }
    }
}

// ---------------- launch ----------------

extern "C" void kernel_launch(void* const* d_in, const int* in_sizes, int n_in,
                              void* d_out, int out_size, void* d_ws, size_t ws_size,
                              hipStream_t stream) {
    const float* user_emb   = (const float*)d_in[0];
    const float* entity_emb = (const float*)d_in[1];
    const float* weight     = (const float*)d_in[2];
    const float* unmask     = (const float*)d_in[3];
    const int*   edge_index = (const int*)d_in[4];
    const int*   edge_type  = (const int*)d_in[5];
    const int*   irows      = (const int*)d_in[6];
    const int*   icols      = (const int*)d_in[7];
    const int* head = edge_index;            // edge_index[0]
    const int* tail = edge_index + N_EDGES;  // edge_index[1]

    char* ws = (char*)d_ws;
    size_t off = 0;
    auto alloc = [&](size_t bytes) -> void* {
        void* p = ws + off;
        off += (bytes + 255) & ~(size_t)255;
        return p;
    };
    uint4* B0     = (uint4*)alloc((size_t)N_ENT * DIM * 2);   // fp16 emb
    uint4* B1     = (uint4*)alloc((size_t)N_ENT * DIM * 2);   // n1 (ent)
    uint4* B2     = (uint4*)alloc((size_t)N_ENT * DIM * 2);   // n2 (ent)
    uint4* U1     = (uint4*)alloc((size_t)N_USERS * DIM * 2); // n1 (usr)
    uint4* U2     = (uint4*)alloc((size_t)N_USERS * DIM * 2); // n2 (usr)
    int*   rp_e   = (int*)alloc((N_ENT + 1) * 4);
    int*   cnt_e  = (int*)alloc((size_t)NREP * N_ENT * 4);    // 3.2 MB
    int*   tot_e  = (int*)alloc(N_ENT * 4);
    int*   rank_e = (int*)alloc((size_t)N_EDGES * 4);
    int2*  ev     = (int2*)alloc((size_t)N_EDGES * 8);
    int*   rp_u   = (int*)alloc((N_USERS + 1) * 4);
    int*   cnt_u  = (int*)alloc((size_t)NREP * N_USERS * 4);  // 1.6 MB
    int*   tot_u  = (int*)alloc(N_USERS * 4);
    int*   rank_u = (int*)alloc((size_t)NNZ * 4);
    int*   col_s  = (int*)alloc((size_t)NNZ * 4);
    int*   bs_e   = (int*)alloc(1024 * 4);
    int*   bs_u   = (int*)alloc(1024 * 4);
    (void)ws_size;

    // --- fp16 conversion of entity table (independent of CSR build) ---
    f32_to_f16<<<(N_ENT * DIM / 8 + 255) / 256, 256, 0, stream>>>(
        (const float4*)entity_emb, B0, N_ENT * DIM / 8);

    // --- CSR build ---
    hipMemsetAsync(cnt_e, 0, (size_t)NREP * N_ENT * 4, stream);
    hipMemsetAsync(cnt_u, 0, (size_t)NREP * N_USERS * 4, stream);
    int grid_edges = (N_EDGES + NNZ + 255) / 256;
    hist_rank_both<<<grid_edges, 256, 0, stream>>>(
        head, irows, cnt_e, cnt_u, rank_e, rank_u);

    replica_fold<<<(N_ENT + N_USERS + 255) / 256, 256, 0, stream>>>(
        cnt_e, cnt_u, tot_e, tot_u);

    int nb_e = (N_ENT + 255) / 256;    // 391
    int nb_u = (N_USERS + 255) / 256;  // 196
    scan_partial<<<nb_e, 256, 0, stream>>>(tot_e, N_ENT, bs_e);
    scan_bsum<<<1, 1024, 0, stream>>>(bs_e, nb_e);
    scan_final<<<nb_e, 256, 0, stream>>>(tot_e, N_ENT, bs_e, rp_e);
    scan_partial<<<nb_u, 256, 0, stream>>>(tot_u, N_USERS, bs_u);
    scan_bsum<<<1, 1024, 0, stream>>>(bs_u, nb_u);
    scan_final<<<nb_u, 256, 0, stream>>>(tot_u, N_USERS, bs_u, rp_u);

    scatter_both<<<grid_edges, 256, 0, stream>>>(
        head, tail, edge_type, unmask,
        rp_e, cnt_e, rank_e, (long long*)ev,
        irows, icols, rp_u, cnt_u, rank_u, col_s);

    // --- 3 hops: h0,h1 write fp16 outputs; h2 fuses residual sum ---
    float* res_e = (float*)d_out;
    float* res_u = res_e + (size_t)N_ENT * DIM;
    const float4* w32 = (const float4*)weight;
    int grid_agg = ((HALF_E + HALF_U) * 64 + 255) / 256;

    agg_hop<0><<<grid_agg, 256, 0, stream>>>(
        B0, w32, rp_e, ev, rp_u, col_s, B1, U1,
        nullptr, nullptr, nullptr, nullptr, nullptr, nullptr, nullptr);
    agg_hop<0><<<grid_agg, 256, 0, stream>>>(
        B1, w32, rp_e, ev, rp_u, col_s, B2, U2,
        nullptr, nullptr, nullptr, nullptr, nullptr, nullptr, nullptr);
    agg_hop<1><<<grid_agg, 256, 0, stream>>>(
        B2, w32, rp_e, ev, rp_u, col_s, nullptr, nullptr,
        B1, U1, U2,
        (const float4*)entity_emb, (const float4*)user_emb,
        (float4*)res_e, (float4*)res_u);
}

// Round 7
// 289.639 us; speedup vs baseline: 4.1753x; 1.5072x over previous
//
#include <hip/hip_runtime.h>
#include <hip/hip_fp16.h>
#include <math.h>

#define N_USERS   50000
#define N_ENT     100000
#define N_EDGES   2000000
#define NNZ       1000000
#define DIM       64
#define N_HOPS    3
#define HALF_E    (N_ENT / 2)
#define HALF_U    (N_USERS / 2)

#define GA     512                    // blocks for bucket hist/scatter passes
#define NB_E   ((N_ENT + 255) >> 8)   // 391 coarse buckets (256 keys each)
#define NB_U   ((N_USERS + 255) >> 8) // 196
#define CAP_D  6400                   // bucket capacity for LDS staging (mean 5120 + 18 sigma)

// ---------------- helpers ----------------

__device__ inline unsigned pack_h2(float x, float y) {
    unsigned lo = __half_as_ushort(__float2half_rn(x));
    unsigned hi = __half_as_ushort(__float2half_rn(y));
    return lo | (hi << 16);
}

__device__ inline float2 unpack_h2(unsigned u) {
    __half2 h = *reinterpret_cast<__half2*>(&u);
    return __half22float2(h);
}

// f32 -> packed fp16 (uint4 = 8 halves from 2 float4)
__global__ void f32_to_f16(const float4* __restrict__ in, uint4* __restrict__ out, int n4) {
    int i = blockIdx.x * blockDim.x + threadIdx.x;
    if (i < n4) {
        float4 a = in[2 * i], b = in[2 * i + 1];
        uint4 o;
        o.x = pack_h2(a.x, a.y);
        o.y = pack_h2(a.z, a.w);
        o.z = pack_h2(b.x, b.y);
        o.w = pack_h2(b.z, b.w);
        out[i] = o;
    }
}

// ---------------- CSR build: two-level LDS counting sort ----------------
// No global atomics anywhere (device atomics = fabric RMW ~24G/s cap, the
// R6 bottleneck). Coarse bucket = key >> 8.

// Pass A: per-block LDS histogram over coarse buckets -> bh[bucket*GA + block]
template <int NBUCKET>
__global__ __launch_bounds__(256) void bucket_hist(const int* __restrict__ key, int n,
                                                   int* __restrict__ bh) {
    __shared__ int h[NBUCKET];
    for (int t = threadIdx.x; t < NBUCKET; t += 256) h[t] = 0;
    __syncthreads();
    int chunk = (n + GA - 1) / GA;
    int s = blockIdx.x * chunk;
    int e = n < s + chunk ? n : s + chunk;
    for (int i = s + threadIdx.x; i < e; i += 256)
        atomicAdd(&h[key[i] >> 8], 1);
    __syncthreads();
    for (int t = threadIdx.x; t < NBUCKET; t += 256)
        bh[t * GA + blockIdx.x] = h[t];
}

// Pass B: 3-kernel exclusive scan over bh (bucket-major) -> off
__global__ void scan_partial(const int* __restrict__ cnt, int n, int* __restrict__ bsum) {
    __shared__ int sd[256];
    int tid = threadIdx.x, i = blockIdx.x * 256 + tid;
    sd[tid] = (i < n) ? cnt[i] : 0;
    __syncthreads();
    for (int s = 128; s > 0; s >>= 1) {
        if (tid < s) sd[tid] += sd[tid + s];
        __syncthreads();
    }
    if (tid == 0) bsum[blockIdx.x] = sd[0];
}

__global__ void scan_bsum(int* bsum, int nb) {
    __shared__ int sd[1024];
    int tid = threadIdx.x;
    int v = (tid < nb) ? bsum[tid] : 0;
    sd[tid] = v;
    __syncthreads();
    for (int o = 1; o < 1024; o <<= 1) {
        int t = (tid >= o) ? sd[tid - o] : 0;
        __syncthreads();
        sd[tid] += t;
        __syncthreads();
    }
    if (tid < nb) bsum[tid] = sd[tid] - v;  // exclusive
}

__global__ void scan_final(const int* __restrict__ cnt, int n,
                           const int* __restrict__ bsum, int* __restrict__ rp) {
    __shared__ int sd[256];
    int tid = threadIdx.x, i = blockIdx.x * 256 + tid;
    int v = (i < n) ? cnt[i] : 0;
    sd[tid] = v;
    __syncthreads();
    for (int o = 1; o < 256; o <<= 1) {
        int t = (tid >= o) ? sd[tid - o] : 0;
        __syncthreads();
        sd[tid] += t;
        __syncthreads();
    }
    int incl = sd[tid] + bsum[blockIdx.x];
    if (i < n) rp[i] = incl - v;
    if (i == n - 1) rp[n] = incl;   // total (so off[NB*GA] = n_edges)
}

// Pass C: scatter payload into bucket-partitioned tmp, LDS-ranked (no atomics
// to global). Key's low 8 bits stored in payload bits 24-31 for pass D.
__global__ __launch_bounds__(256) void bucket_scatter_e(
    const int* __restrict__ head, const int* __restrict__ tail,
    const int* __restrict__ etype, const float* __restrict__ unmask,
    const int* __restrict__ off, long long* __restrict__ tmp) {
    __shared__ int h[NB_E];
    __shared__ int boff[NB_E];
    for (int t = threadIdx.x; t < NB_E; t += 256) { h[t] = 0; boff[t] = off[t * GA + blockIdx.x]; }
    __syncthreads();
    int chunk = (N_EDGES + GA - 1) / GA;
    int s = blockIdx.x * chunk;
    int e = N_EDGES < s + chunk ? N_EDGES : s + chunk;
    for (int i = s + threadIdx.x; i < e; i += 256) {
        int k = head[i];
        int b = k >> 8;
        int local = atomicAdd(&h[b], 1);
        unsigned lo = (unsigned)(tail[i] | ((etype[i] - 1) << 20) | ((k & 255) << 24));
        unsigned hi = (unsigned)__float_as_int(unmask[i]);
        tmp[boff[b] + local] = (long long)(((unsigned long long)hi << 32) | lo);
    }
}

__global__ __launch_bounds__(256) void bucket_scatter_u(
    const int* __restrict__ rows, const int* __restrict__ cols,
    const int* __restrict__ off, int* __restrict__ tmp) {
    __shared__ int h[NB_U];
    __shared__ int boff[NB_U];
    for (int t = threadIdx.x; t < NB_U; t += 256) { h[t] = 0; boff[t] = off[t * GA + blockIdx.x]; }
    __syncthreads();
    int chunk = (NNZ + GA - 1) / GA;
    int s = blockIdx.x * chunk;
    int e = NNZ < s + chunk ? NNZ : s + chunk;
    for (int i = s + threadIdx.x; i < e; i += 256) {
        int k = rows[i];
        int b = k >> 8;
        int local = atomicAdd(&h[b], 1);
        tmp[boff[b] + local] = cols[i] | ((k & 255) << 24);
    }
}

// Pass D: one block per bucket. LDS 256-key hist + scan -> rp; LDS-staged
// sort; coalesced final write (key bits stripped).
__global__ __launch_bounds__(256) void bucket_sort_e(
    const int* __restrict__ off, const long long* __restrict__ tmp,
    long long* __restrict__ ev, int* __restrict__ rp) {
    __shared__ int khist[256];
    __shared__ int koff[256];
    __shared__ long long stage[CAP_D];
    int b = blockIdx.x;
    int sb = off[b * GA];
    int se = off[(b + 1) * GA];   // off[NB_E*GA] = N_EDGES (scan total)
    int len = se - sb;
    int t = threadIdx.x;
    khist[t] = 0;
    __syncthreads();
    for (int i = t; i < len; i += 256)
        atomicAdd(&khist[(int)(((unsigned long long)tmp[sb + i] >> 24) & 255)], 1);
    __syncthreads();
    int v = khist[t];
    koff[t] = v;
    __syncthreads();
    for (int o = 1; o < 256; o <<= 1) {
        int x = (t >= o) ? koff[t - o] : 0;
        __syncthreads();
        koff[t] += x;
        __syncthreads();
    }
    int excl = koff[t] - v;
    int key = b * 256 + t;
    if (key < N_ENT) rp[key] = sb + excl;
    if (b == 0 && t == 0) rp[N_ENT] = N_EDGES;
    khist[t] = excl;   // cursor
    __syncthreads();
    if (len <= CAP_D) {
        for (int i = t; i < len; i += 256) {
            long long v2 = tmp[sb + i];
            int k = (int)(((unsigned long long)v2 >> 24) & 255);
            int p = atomicAdd(&khist[k], 1);
            stage[p] = v2;
        }
        __syncthreads();
        for (int i = t; i < len; i += 256)
            ev[sb + i] = stage[i] & (long long)0xFFFFFFFF00FFFFFFULL;
    } else {  // overflow fallback (statistically unreachable)
        for (int i = t; i < len; i += 256) {
            long long v2 = tmp[sb + i];
            int k = (int)(((unsigned long long)v2 >> 24) & 255);
            int p = atomicAdd(&khist[k], 1);
            ev[sb + p] = v2 & (long long)0xFFFFFFFF00FFFFFFULL;
        }
    }
}

__global__ __launch_bounds__(256) void bucket_sort_u(
    const int* __restrict__ off, const int* __restrict__ tmp,
    int* __restrict__ col_s, int* __restrict__ rp) {
    __shared__ int khist[256];
    __shared__ int koff[256];
    __shared__ int stage[CAP_D];
    int b = blockIdx.x;
    int sb = off[b * GA];
    int se = off[(b + 1) * GA];   // off[NB_U*GA] = NNZ
    int len = se - sb;
    int t = threadIdx.x;
    khist[t] = 0;
    __syncthreads();
    for (int i = t; i < len; i += 256)
        atomicAdd(&khist[(tmp[sb + i] >> 24) & 255], 1);
    __syncthreads();
    int v = khist[t];
    koff[t] = v;
    __syncthreads();
    for (int o = 1; o < 256; o <<= 1) {
        int x = (t >= o) ? koff[t - o] : 0;
        __syncthreads();
        koff[t] += x;
        __syncthreads();
    }
    int excl = koff[t] - v;
    int key = b * 256 + t;
    if (key < N_USERS) rp[key] = sb + excl;
    if (b == 0 && t == 0) rp[N_USERS] = NNZ;
    khist[t] = excl;
    __syncthreads();
    if (len <= CAP_D) {
        for (int i = t; i < len; i += 256) {
            int v2 = tmp[sb + i];
            int p = atomicAdd(&khist[(v2 >> 24) & 255], 1);
            stage[p] = v2;
        }
        __syncthreads();
        for (int i = t; i < len; i += 256)
            col_s[sb + i] = stage[i] & 0x00FFFFFF;
    } else {
        for (int i = t; i < len; i += 256) {
            int v2 = tmp[sb + i];
            int p = atomicAdd(&khist[(v2 >> 24) & 255], 1);
            col_s[sb + p] = v2 & 0x00FFFFFF;
        }
    }
}

// ---------------- fused per-hop aggregate + normalize ----------------
// 2 rows per wave: lanes 0-31 row A, 32-63 row B. Within a 32-half:
// 4 edge slots x 8 lanes (uint4 = 8 fp16 dims per lane), unrolled x2
// -> 8 edges in flight per row per iter. Weight table stays f32 (L1).
// FINAL=0: write fp16 hop output. FINAL=1: fuse res = emb + n1 + n2 + n3.

__device__ inline void edge_body(const uint4* __restrict__ in16,
                                 const float4* __restrict__ w32,
                                 int ex, float sc, int sub, float (&acc)[8]) {
    int t = ex & 0xFFFFF, rt = (ex >> 20) & 15;
    uint4 r4 = in16[(size_t)t * 8 + sub];
    float4 wa = w32[rt * 16 + sub * 2];
    float4 wb = w32[rt * 16 + sub * 2 + 1];
    float2 r0 = unpack_h2(r4.x), r1 = unpack_h2(r4.y);
    float2 r2 = unpack_h2(r4.z), r3 = unpack_h2(r4.w);
    acc[0] = fmaf(r0.x * sc, wa.x, acc[0]);
    acc[1] = fmaf(r0.y * sc, wa.y, acc[1]);
    acc[2] = fmaf(r1.x * sc, wa.z, acc[2]);
    acc[3] = fmaf(r1.y * sc, wa.w, acc[3]);
    acc[4] = fmaf(r2.x * sc, wb.x, acc[4]);
    acc[5] = fmaf(r2.y * sc, wb.y, acc[5]);
    acc[6] = fmaf(r3.x * sc, wb.z, acc[6]);
    acc[7] = fmaf(r3.y * sc, wb.w, acc[7]);
}

template <int FINAL>
__global__ __launch_bounds__(256) void agg_hop(
    const uint4* __restrict__ in16, const float4* __restrict__ w32,
    const int* __restrict__ rp_e, const int2* __restrict__ ev,
    const int* __restrict__ rp_u, const int* __restrict__ col_s,
    uint4* __restrict__ oute, uint4* __restrict__ outu,
    const uint4* __restrict__ pe1, const uint4* __restrict__ pu1,
    const uint4* __restrict__ pu2,
    const float4* __restrict__ emb_e, const float4* __restrict__ emb_u,
    float4* __restrict__ res_e, float4* __restrict__ res_u) {
    int gwave = (blockIdx.x * blockDim.x + threadIdx.x) >> 6;
    if (gwave >= HALF_E + HALF_U) return;
    int lane = threadIdx.x & 63;
    int half = lane >> 5;
    int grp = (lane >> 3) & 3;   // edge slot 0..3 within the 32-half
    int sub = lane & 7;          // uint4 index within fp16 row

    bool is_ent = gwave < HALF_E;
    int row = is_ent ? gwave * 2 + half : (gwave - HALF_E) * 2 + half;
    const int* __restrict__ rp = is_ent ? rp_e : rp_u;
    int beg = rp[row], end = rp[row + 1];

    float acc[8];
#pragma unroll
    for (int j = 0; j < 8; ++j) acc[j] = 0.f;

    if (is_ent) {
        for (int p0 = beg; p0 < end; p0 += 8) {
            int pA = p0 + grp, pB = p0 + 4 + grp;
            int2 eA = (pA < end) ? ev[pA] : make_int2(0, 0);
            int2 eB = (pB < end) ? ev[pB] : make_int2(0, 0);
            edge_body(in16, w32, eA.x, __int_as_float(eA.y), sub, acc);
            edge_body(in16, w32, eB.x, __int_as_float(eB.y), sub, acc);
        }
    } else {
        for (int p0 = beg; p0 < end; p0 += 8) {
            int pA = p0 + grp, pB = p0 + 4 + grp;
            int cA = 0, cB = 0;
            float mA = 0.f, mB = 0.f;
            if (pA < end) { cA = col_s[pA]; mA = 1.f; }
            if (pB < end) { cB = col_s[pB]; mB = 1.f; }
            {
                uint4 r4 = in16[(size_t)cA * 8 + sub];
                float2 r0 = unpack_h2(r4.x), r1 = unpack_h2(r4.y);
                float2 r2 = unpack_h2(r4.z), r3 = unpack_h2(r4.w);
                acc[0] = fmaf(r0.x, mA, acc[0]); acc[1] = fmaf(r0.y, mA, acc[1]);
                acc[2] = fmaf(r1.x, mA, acc[2]); acc[3] = fmaf(r1.y, mA, acc[3]);
                acc[4] = fmaf(r2.x, mA, acc[4]); acc[5] = fmaf(r2.y, mA, acc[5]);
                acc[6] = fmaf(r3.x, mA, acc[6]); acc[7] = fmaf(r3.y, mA, acc[7]);
            }
            {
                uint4 r4 = in16[(size_t)cB * 8 + sub];
                float2 r0 = unpack_h2(r4.x), r1 = unpack_h2(r4.y);
                float2 r2 = unpack_h2(r4.z), r3 = unpack_h2(r4.w);
                acc[0] = fmaf(r0.x, mB, acc[0]); acc[1] = fmaf(r0.y, mB, acc[1]);
                acc[2] = fmaf(r1.x, mB, acc[2]); acc[3] = fmaf(r1.y, mB, acc[3]);
                acc[4] = fmaf(r2.x, mB, acc[4]); acc[5] = fmaf(r2.y, mB, acc[5]);
                acc[6] = fmaf(r3.x, mB, acc[6]); acc[7] = fmaf(r3.y, mB, acc[7]);
            }
        }
    }

    // fold the 4 edge slots (stays within each 32-half: offsets 8, 16)
#pragma unroll
    for (int j = 0; j < 8; ++j) {
        acc[j] += __shfl_xor(acc[j], 8, 64);
        acc[j] += __shfl_xor(acc[j], 16, 64);
    }
    float ss = 0.f;
#pragma unroll
    for (int j = 0; j < 8; ++j) ss = fmaf(acc[j], acc[j], ss);
    ss += __shfl_xor(ss, 1, 64);
    ss += __shfl_xor(ss, 2, 64);
    ss += __shfl_xor(ss, 4, 64);
    float inv = 1.0f / fmaxf(sqrtf(ss), 1e-12f);

    if (grp == 0) {
        float n0 = acc[0] * inv, n1 = acc[1] * inv, n2 = acc[2] * inv, n3 = acc[3] * inv;
        float n4 = acc[4] * inv, n5 = acc[5] * inv, n6 = acc[6] * inv, n7 = acc[7] * inv;
        if constexpr (!FINAL) {
            uint4 p;
            p.x = pack_h2(n0, n1); p.y = pack_h2(n2, n3);
            p.z = pack_h2(n4, n5); p.w = pack_h2(n6, n7);
            (is_ent ? oute : outu)[(size_t)row * 8 + sub] = p;
        } else {
            const uint4* q1p = is_ent ? pe1 : pu1;   // hop-1 output
            const uint4* q2p = is_ent ? in16 : pu2;  // hop-2 output (entity: own input)
            uint4 q1 = q1p[(size_t)row * 8 + sub];
            uint4 q2 = q2p[(size_t)row * 8 + sub];
            const float4* emb = is_ent ? emb_e : emb_u;
            float4* res = is_ent ? res_e : res_u;
            size_t rb = (size_t)row * 16 + sub * 2;
            float4 a = emb[rb], b = emb[rb + 1];
            float2 x0 = unpack_h2(q1.x), x1 = unpack_h2(q1.y);
            float2 x2 = unpack_h2(q1.z), x3 = unpack_h2(q1.w);
            float2 y0 = unpack_h2(q2.x), y1 = unpack_h2(q2.y);
            float2 y2 = unpack_h2(q2.z), y3 = unpack_h2(q2.w);
            a.x += n0 + x0.x + y0.x;  a.y += n1 + x0.y + y0.y;
            a.z += n2 + x1.x + y1.x;  a.w += n3 + x1.y + y1.y;
            b.x += n4 + x2.x + y2.x;  b.y += n5 + x2.y + y2.y;
            b.z += n6 + x3.x + y3.x;  b.w += n7 + x3.y + y3.y;
            res[rb] = a;
            res[rb + 1] = b;
        }
    }
}

// ---------------- launch ----------------

extern "C" void kernel_launch(void* const* d_in, const int* in_sizes, int n_in,
                              void* d_out, int out_size, void* d_ws, size_t ws_size,
                              hipStream_t stream) {
    const float* user_emb   = (const float*)d_in[0];
    const float* entity_emb = (const float*)d_in[1];
    const float* weight     = (const float*)d_in[2];
    const float* unmask     = (const float*)d_in[3];
    const int*   edge_index = (const int*)d_in[4];
    const int*   edge_type  = (const int*)d_in[5];
    const int*   irows      = (const int*)d_in[6];
    const int*   icols      = (const int*)d_in[7];
    const int* head = edge_index;            // edge_index[0]
    const int* tail = edge_index + N_EDGES;  // edge_index[1]

    char* ws = (char*)d_ws;
    size_t off = 0;
    auto alloc = [&](size_t bytes) -> void* {
        void* p = ws + off;
        off += (bytes + 255) & ~(size_t)255;
        return p;
    };
    uint4* B0     = (uint4*)alloc((size_t)N_ENT * DIM * 2);   // fp16 emb
    uint4* B1     = (uint4*)alloc((size_t)N_ENT * DIM * 2);   // n1 (ent)
    uint4* B2     = (uint4*)alloc((size_t)N_ENT * DIM * 2);   // n2 (ent)
    uint4* U1     = (uint4*)alloc((size_t)N_USERS * DIM * 2); // n1 (usr)
    uint4* U2     = (uint4*)alloc((size_t)N_USERS * DIM * 2); // n2 (usr)
    int*   rp_e   = (int*)alloc((N_ENT + 1) * 4);
    int*   rp_u   = (int*)alloc((N_USERS + 1) * 4);
    long long* ev     = (long long*)alloc((size_t)N_EDGES * 8);
    long long* tmp_ev = (long long*)alloc((size_t)N_EDGES * 8);
    int*   col_s   = (int*)alloc((size_t)NNZ * 4);
    int*   tmp_col = (int*)alloc((size_t)NNZ * 4);
    int*   bh_e   = (int*)alloc((size_t)(NB_E * GA + 1) * 4);
    int*   off_e  = (int*)alloc((size_t)(NB_E * GA + 1) * 4);
    int*   bh_u   = (int*)alloc((size_t)(NB_U * GA + 1) * 4);
    int*   off_u  = (int*)alloc((size_t)(NB_U * GA + 1) * 4);
    int*   bs     = (int*)alloc(1024 * 4);
    (void)ws_size;

    // --- fp16 conversion of entity table (independent of CSR build) ---
    f32_to_f16<<<(N_ENT * DIM / 8 + 255) / 256, 256, 0, stream>>>(
        (const float4*)entity_emb, B0, N_ENT * DIM / 8);

    // --- CSR build: LDS counting sort, zero global atomics ---
    bucket_hist<NB_E><<<GA, 256, 0, stream>>>(head, N_EDGES, bh_e);
    int n_e = NB_E * GA, nb_e = (n_e + 255) / 256;   // 782 blocks
    scan_partial<<<nb_e, 256, 0, stream>>>(bh_e, n_e, bs);
    scan_bsum<<<1, 1024, 0, stream>>>(bs, nb_e);
    scan_final<<<nb_e, 256, 0, stream>>>(bh_e, n_e, bs, off_e);
    bucket_scatter_e<<<GA, 256, 0, stream>>>(head, tail, edge_type, unmask, off_e, tmp_ev);
    bucket_sort_e<<<NB_E, 256, 0, stream>>>(off_e, tmp_ev, ev, rp_e);

    bucket_hist<NB_U><<<GA, 256, 0, stream>>>(irows, NNZ, bh_u);
    int n_u = NB_U * GA, nb_u = (n_u + 255) / 256;   // 392 blocks
    scan_partial<<<nb_u, 256, 0, stream>>>(bh_u, n_u, bs);
    scan_bsum<<<1, 1024, 0, stream>>>(bs, nb_u);
    scan_final<<<nb_u, 256, 0, stream>>>(bh_u, n_u, bs, off_u);
    bucket_scatter_u<<<GA, 256, 0, stream>>>(irows, icols, off_u, tmp_col);
    bucket_sort_u<<<NB_U, 256, 0, stream>>>(off_u, tmp_col, col_s, rp_u);

    // --- 3 hops: h0,h1 write fp16 outputs; h2 fuses residual sum ---
    float* res_e = (float*)d_out;
    float* res_u = res_e + (size_t)N_ENT * DIM;
    const float4* w32 = (const float4*)weight;
    int grid_agg = ((HALF_E + HALF_U) * 64 + 255) / 256;

    agg_hop<0><<<grid_agg, 256, 0, stream>>>(
        B0, w32, rp_e, (const int2*)ev, rp_u, col_s, B1, U1,
        nullptr, nullptr, nullptr, nullptr, nullptr, nullptr, nullptr);
    agg_hop<0><<<grid_agg, 256, 0, stream>>>(
        B1, w32, rp_e, (const int2*)ev, rp_u, col_s, B2, U2,
        nullptr, nullptr, nullptr, nullptr, nullptr, nullptr, nullptr);
    agg_hop<1><<<grid_agg, 256, 0, stream>>>(
        B2, w32, rp_e, (const int2*)ev, rp_u, col_s, nullptr, nullptr,
        B1, U1, U2,
        (const float4*)entity_emb, (const float4*)user_emb,
        (float4*)res_e, (float4*)res_u);
}

// Round 8
// 249.003 us; speedup vs baseline: 4.8567x; 1.1632x over previous
//
#include <hip/hip_runtime.h>
#include <hip/hip_fp16.h>
#include <math.h>

#define N_USERS   50000
#define N_ENT     100000
#define N_EDGES   2000000
#define NNZ       1000000
#define DIM       64
#define HALF_E    (N_ENT / 2)
#define HALF_U    (N_USERS / 2)

#define GA      512                    // blocks per side for bucket hist/scatter
#define NB_E    391                    // coarse buckets (256 keys each) entity
#define NB_U    196                    // user
#define NALL_E  (NB_E * GA)            // 200192
#define NALL_U  (NB_U * GA)            // 100352
#define NALL    (NALL_E + NALL_U)      // 300544
#define NB_SCAN (NALL / 512)           // 587 (exact)
#define CAP_D   6400                   // bucket capacity (mean 5120 + 18 sigma)

// ---------------- helpers ----------------

__device__ inline unsigned pack_h2(float x, float y) {
    unsigned lo = __half_as_ushort(__float2half_rn(x));
    unsigned hi = __half_as_ushort(__float2half_rn(y));
    return lo | (hi << 16);
}

__device__ inline float2 unpack_h2(unsigned u) {
    __half2 h = *reinterpret_cast<__half2*>(&u);
    return __half22float2(h);
}

__device__ inline __half2 bits_h2(unsigned u) { return *reinterpret_cast<__half2*>(&u); }

__device__ inline __half2 shfl_h2(__half2 v, int o) {
    int x = *reinterpret_cast<int*>(&v);
    x = __shfl_xor(x, o, 64);
    return *reinterpret_cast<__half2*>(&x);
}

// f32 -> packed fp16 (uint4 = 8 halves from 2 float4)
__global__ void f32_to_f16(const float4* __restrict__ in, uint4* __restrict__ out, int n4) {
    int i = blockIdx.x * blockDim.x + threadIdx.x;
    if (i < n4) {
        float4 a = in[2 * i], b = in[2 * i + 1];
        uint4 o;
        o.x = pack_h2(a.x, a.y);
        o.y = pack_h2(a.z, a.w);
        o.z = pack_h2(b.x, b.y);
        o.w = pack_h2(b.z, b.w);
        out[i] = o;
    }
}

// ---------------- CSR build: two-level LDS counting sort (no global atomics) ----------------
// Coarse bucket = key >> 8. E and U sides merged per pass.

__global__ __launch_bounds__(256) void bucket_hist_both(
    const int* __restrict__ head, const int* __restrict__ irows, int* __restrict__ bh) {
    __shared__ int h[NB_E];
    bool isE = blockIdx.x < GA;
    int b = isE ? blockIdx.x : blockIdx.x - GA;
    const int* key = isE ? head : irows;
    int n = isE ? N_EDGES : NNZ;
    int nbuck = isE ? NB_E : NB_U;
    int base = isE ? 0 : NALL_E;
    for (int t = threadIdx.x; t < nbuck; t += 256) h[t] = 0;
    __syncthreads();
    int chunk = (n + GA - 1) / GA;
    int s = b * chunk;
    int e = n < s + chunk ? n : s + chunk;
    for (int i = s + threadIdx.x; i < e; i += 256)
        atomicAdd(&h[key[i] >> 8], 1);
    __syncthreads();
    for (int t = threadIdx.x; t < nbuck; t += 256)
        bh[base + t * GA + b] = h[t];
}

// 3-kernel exclusive scan over the concatenated count array (512-thr blocks)
__global__ void scan_partial(const int* __restrict__ cnt, int n, int* __restrict__ bsum) {
    __shared__ int sd[512];
    int tid = threadIdx.x, i = blockIdx.x * 512 + tid;
    sd[tid] = (i < n) ? cnt[i] : 0;
    __syncthreads();
    for (int s = 256; s > 0; s >>= 1) {
        if (tid < s) sd[tid] += sd[tid + s];
        __syncthreads();
    }
    if (tid == 0) bsum[blockIdx.x] = sd[0];
}

__global__ void scan_bsum(int* bsum, int nb) {
    __shared__ int sd[1024];
    int tid = threadIdx.x;
    int v = (tid < nb) ? bsum[tid] : 0;
    sd[tid] = v;
    __syncthreads();
    for (int o = 1; o < 1024; o <<= 1) {
        int t = (tid >= o) ? sd[tid - o] : 0;
        __syncthreads();
        sd[tid] += t;
        __syncthreads();
    }
    if (tid < nb) bsum[tid] = sd[tid] - v;  // exclusive
}

__global__ void scan_final(const int* __restrict__ cnt, int n,
                           const int* __restrict__ bsum, int* __restrict__ rp) {
    __shared__ int sd[512];
    int tid = threadIdx.x, i = blockIdx.x * 512 + tid;
    int v = (i < n) ? cnt[i] : 0;
    sd[tid] = v;
    __syncthreads();
    for (int o = 1; o < 512; o <<= 1) {
        int t = (tid >= o) ? sd[tid - o] : 0;
        __syncthreads();
        sd[tid] += t;
        __syncthreads();
    }
    int incl = sd[tid] + bsum[blockIdx.x];
    if (i < n) rp[i] = incl - v;
    if (i == n - 1) rp[n] = incl;
}

// scatter payload into bucket-partitioned tmp (LDS-ranked). Key low 8 bits in
// payload bits 24-31 for the sort pass. unmask stored as replicated half2.
__global__ __launch_bounds__(256) void bucket_scatter_both(
    const int* __restrict__ head, const int* __restrict__ tail,
    const int* __restrict__ etype, const float* __restrict__ unmask,
    const int* __restrict__ irows, const int* __restrict__ icols,
    const int* __restrict__ off, long long* __restrict__ tmp_ev,
    int* __restrict__ tmp_col) {
    __shared__ int h[NB_E];
    __shared__ int boff[NB_E];
    bool isE = blockIdx.x < GA;
    int b = isE ? blockIdx.x : blockIdx.x - GA;
    if (isE) {
        for (int t = threadIdx.x; t < NB_E; t += 256) { h[t] = 0; boff[t] = off[t * GA + b]; }
        __syncthreads();
        int chunk = (N_EDGES + GA - 1) / GA;
        int s = b * chunk;
        int e = N_EDGES < s + chunk ? N_EDGES : s + chunk;
        for (int i = s + threadIdx.x; i < e; i += 256) {
            int k = head[i];
            int bk = k >> 8;
            int local = atomicAdd(&h[bk], 1);
            unsigned hh = __half_as_ushort(__float2half_rn(unmask[i]));
            unsigned hi = hh | (hh << 16);
            unsigned lo = (unsigned)(tail[i] | ((etype[i] - 1) << 20) | ((k & 255) << 24));
            tmp_ev[boff[bk] + local] = (long long)(((unsigned long long)hi << 32) | lo);
        }
    } else {
        for (int t = threadIdx.x; t < NB_U; t += 256) { h[t] = 0; boff[t] = off[NALL_E + t * GA + b] - N_EDGES; }
        __syncthreads();
        int chunk = (NNZ + GA - 1) / GA;
        int s = b * chunk;
        int e = NNZ < s + chunk ? NNZ : s + chunk;
        for (int i = s + threadIdx.x; i < e; i += 256) {
            int k = irows[i];
            int bk = k >> 8;
            int local = atomicAdd(&h[bk], 1);
            tmp_col[boff[bk] + local] = icols[i] | ((k & 255) << 24);
        }
    }
}

// one block per bucket: LDS 256-key hist + scan -> rp; LDS-staged sort;
// coalesced final write with key bits stripped.
__global__ __launch_bounds__(256) void bucket_sort_both(
    const int* __restrict__ off, const long long* __restrict__ tmp_ev,
    const int* __restrict__ tmp_col, long long* __restrict__ ev,
    int* __restrict__ col_s, int* __restrict__ rp_e, int* __restrict__ rp_u) {
    __shared__ int khist[256];
    __shared__ int koff[256];
    __shared__ long long stage[CAP_D];
    int t = threadIdx.x;
    bool isE = blockIdx.x < NB_E;
    if (isE) {
        int b = blockIdx.x;
        int sb = off[b * GA], se = off[(b + 1) * GA];
        int len = se - sb;
        khist[t] = 0;
        __syncthreads();
        for (int i = t; i < len; i += 256)
            atomicAdd(&khist[(int)(((unsigned long long)tmp_ev[sb + i] >> 24) & 255)], 1);
        __syncthreads();
        int v = khist[t];
        koff[t] = v;
        __syncthreads();
        for (int o = 1; o < 256; o <<= 1) {
            int x = (t >= o) ? koff[t - o] : 0;
            __syncthreads();
            koff[t] += x;
            __syncthreads();
        }
        int excl = koff[t] - v;
        int key = b * 256 + t;
        if (key < N_ENT) rp_e[key] = sb + excl;
        if (b == 0 && t == 0) rp_e[N_ENT] = N_EDGES;
        khist[t] = excl;
        __syncthreads();
        if (len <= CAP_D) {
            for (int i = t; i < len; i += 256) {
                long long v2 = tmp_ev[sb + i];
                int k = (int)(((unsigned long long)v2 >> 24) & 255);
                int p = atomicAdd(&khist[k], 1);
                stage[p] = v2;
            }
            __syncthreads();
            for (int i = t; i < len; i += 256)
                ev[sb + i] = stage[i] & (long long)0xFFFFFFFF00FFFFFFULL;
        } else {
            for (int i = t; i < len; i += 256) {
                long long v2 = tmp_ev[sb + i];
                int k = (int)(((unsigned long long)v2 >> 24) & 255);
                int p = atomicAdd(&khist[k], 1);
                ev[sb + p] = v2 & (long long)0xFFFFFFFF00FFFFFFULL;
            }
        }
    } else {
        int b = blockIdx.x - NB_E;
        int sb = off[NALL_E + b * GA] - N_EDGES;
        int se = off[NALL_E + (b + 1) * GA] - N_EDGES;
        int len = se - sb;
        int* stage32 = (int*)stage;
        khist[t] = 0;
        __syncthreads();
        for (int i = t; i < len; i += 256)
            atomicAdd(&khist[(tmp_col[sb + i] >> 24) & 255], 1);
        __syncthreads();
        int v = khist[t];
        koff[t] = v;
        __syncthreads();
        for (int o = 1; o < 256; o <<= 1) {
            int x = (t >= o) ? koff[t - o] : 0;
            __syncthreads();
            koff[t] += x;
            __syncthreads();
        }
        int excl = koff[t] - v;
        int key = b * 256 + t;
        if (key < N_USERS) rp_u[key] = sb + excl;
        if (b == 0 && t == 0) rp_u[N_USERS] = NNZ;
        khist[t] = excl;
        __syncthreads();
        if (len <= CAP_D) {
            for (int i = t; i < len; i += 256) {
                int v2 = tmp_col[sb + i];
                int p = atomicAdd(&khist[(v2 >> 24) & 255], 1);
                stage32[p] = v2;
            }
            __syncthreads();
            for (int i = t; i < len; i += 256)
                col_s[sb + i] = stage32[i] & 0x00FFFFFF;
        } else {
            for (int i = t; i < len; i += 256) {
                int v2 = tmp_col[sb + i];
                int p = atomicAdd(&khist[(v2 >> 24) & 255], 1);
                col_s[sb + p] = v2 & 0x00FFFFFF;
            }
        }
    }
}

// ---------------- fused per-hop aggregate + normalize ----------------
// 2 rows per wave (lanes 0-31 / 32-63); per 32-half: 4 edge slots x 8 lanes,
// unrolled x2 -> 8 edges in flight per row. ALL edge-loop math is packed fp16
// (v_pk_mul/v_pk_fma); f32 only for the per-row normalize + residual.
// FINAL=0: write fp16 hop output. FINAL=1: fuse res = emb + n1 + n2 + n3.

__device__ inline void edge_body16(const uint4* __restrict__ in16,
                                   const uint4* __restrict__ w16,
                                   int ex, unsigned scbits, int sub, __half2 (&acc)[4]) {
    int tt = ex & 0xFFFFF, rt = (ex >> 20) & 15;
    uint4 r4 = in16[(size_t)tt * 8 + sub];
    uint4 w4 = w16[rt * 8 + sub];
    __half2 sc2 = bits_h2(scbits);
    acc[0] = __hfma2(__hmul2(bits_h2(r4.x), sc2), bits_h2(w4.x), acc[0]);
    acc[1] = __hfma2(__hmul2(bits_h2(r4.y), sc2), bits_h2(w4.y), acc[1]);
    acc[2] = __hfma2(__hmul2(bits_h2(r4.z), sc2), bits_h2(w4.z), acc[2]);
    acc[3] = __hfma2(__hmul2(bits_h2(r4.w), sc2), bits_h2(w4.w), acc[3]);
}

template <int FINAL>
__global__ __launch_bounds__(256) void agg_hop(
    const uint4* __restrict__ in16, const uint4* __restrict__ w16,
    const int* __restrict__ rp_e, const int2* __restrict__ ev,
    const int* __restrict__ rp_u, const int* __restrict__ col_s,
    uint4* __restrict__ oute, uint4* __restrict__ outu,
    const uint4* __restrict__ pe1, const uint4* __restrict__ pu1,
    const uint4* __restrict__ pu2,
    const float4* __restrict__ emb_e, const float4* __restrict__ emb_u,
    float4* __restrict__ res_e, float4* __restrict__ res_u) {
    int gwave = (blockIdx.x * blockDim.x + threadIdx.x) >> 6;
    if (gwave >= HALF_E + HALF_U) return;
    int lane = threadIdx.x & 63;
    int half = lane >> 5;
    int grp = (lane >> 3) & 3;   // edge slot 0..3 within the 32-half
    int sub = lane & 7;          // uint4 index within fp16 row

    bool is_ent = gwave < HALF_E;
    int row = is_ent ? gwave * 2 + half : (gwave - HALF_E) * 2 + half;
    const int* __restrict__ rp = is_ent ? rp_e : rp_u;
    int beg = rp[row], end = rp[row + 1];

    __half2 acc[4];
#pragma unroll
    for (int j = 0; j < 4; ++j) acc[j] = bits_h2(0u);

    if (is_ent) {
        for (int p0 = beg; p0 < end; p0 += 8) {
            int pA = p0 + grp, pB = p0 + 4 + grp;
            int2 eA = (pA < end) ? ev[pA] : make_int2(0, 0);
            int2 eB = (pB < end) ? ev[pB] : make_int2(0, 0);
            edge_body16(in16, w16, eA.x, (unsigned)eA.y, sub, acc);
            edge_body16(in16, w16, eB.x, (unsigned)eB.y, sub, acc);
        }
    } else {
        for (int p0 = beg; p0 < end; p0 += 8) {
            int pA = p0 + grp, pB = p0 + 4 + grp;
            int cA = 0, cB = 0;
            unsigned mAb = 0u, mBb = 0u;
            if (pA < end) { cA = col_s[pA]; mAb = 0x3C003C00u; }
            if (pB < end) { cB = col_s[pB]; mBb = 0x3C003C00u; }
            __half2 mA = bits_h2(mAb), mB = bits_h2(mBb);
            {
                uint4 r4 = in16[(size_t)cA * 8 + sub];
                acc[0] = __hfma2(bits_h2(r4.x), mA, acc[0]);
                acc[1] = __hfma2(bits_h2(r4.y), mA, acc[1]);
                acc[2] = __hfma2(bits_h2(r4.z), mA, acc[2]);
                acc[3] = __hfma2(bits_h2(r4.w), mA, acc[3]);
            }
            {
                uint4 r4 = in16[(size_t)cB * 8 + sub];
                acc[0] = __hfma2(bits_h2(r4.x), mB, acc[0]);
                acc[1] = __hfma2(bits_h2(r4.y), mB, acc[1]);
                acc[2] = __hfma2(bits_h2(r4.z), mB, acc[2]);
                acc[3] = __hfma2(bits_h2(r4.w), mB, acc[3]);
            }
        }
    }

    // fold the 4 edge slots (within each 32-half: offsets 8, 16), packed
#pragma unroll
    for (int j = 0; j < 4; ++j) {
        acc[j] = __hadd2(acc[j], shfl_h2(acc[j], 8));
        acc[j] = __hadd2(acc[j], shfl_h2(acc[j], 16));
    }
    // to f32 for normalize
    float2 f0 = __half22float2(acc[0]), f1 = __half22float2(acc[1]);
    float2 f2 = __half22float2(acc[2]), f3 = __half22float2(acc[3]);
    float ss = f0.x * f0.x + f0.y * f0.y + f1.x * f1.x + f1.y * f1.y +
               f2.x * f2.x + f2.y * f2.y + f3.x * f3.x + f3.y * f3.y;
    ss += __shfl_xor(ss, 1, 64);
    ss += __shfl_xor(ss, 2, 64);
    ss += __shfl_xor(ss, 4, 64);
    float inv = 1.0f / fmaxf(sqrtf(ss), 1e-12f);

    if (grp == 0) {
        float n0 = f0.x * inv, n1 = f0.y * inv, n2 = f1.x * inv, n3 = f1.y * inv;
        float n4 = f2.x * inv, n5 = f2.y * inv, n6 = f3.x * inv, n7 = f3.y * inv;
        if constexpr (!FINAL) {
            uint4 p;
            p.x = pack_h2(n0, n1); p.y = pack_h2(n2, n3);
            p.z = pack_h2(n4, n5); p.w = pack_h2(n6, n7);
            (is_ent ? oute : outu)[(size_t)row * 8 + sub] = p;
        } else {
            const uint4* q1p = is_ent ? pe1 : pu1;   // hop-1 output
            const uint4* q2p = is_ent ? in16 : pu2;  // hop-2 output (entity: own input)
            uint4 q1 = q1p[(size_t)row * 8 + sub];
            uint4 q2 = q2p[(size_t)row * 8 + sub];
            const float4* emb = is_ent ? emb_e : emb_u;
            float4* res = is_ent ? res_e : res_u;
            size_t rb = (size_t)row * 16 + sub * 2;
            float4 a = emb[rb], b = emb[rb + 1];
            float2 x0 = unpack_h2(q1.x), x1 = unpack_h2(q1.y);
            float2 x2 = unpack_h2(q1.z), x3 = unpack_h2(q1.w);
            float2 y0 = unpack_h2(q2.x), y1 = unpack_h2(q2.y);
            float2 y2 = unpack_h2(q2.z), y3 = unpack_h2(q2.w);
            a.x += n0 + x0.x + y0.x;  a.y += n1 + x0.y + y0.y;
            a.z += n2 + x1.x + y1.x;  a.w += n3 + x1.y + y1.y;
            b.x += n4 + x2.x + y2.x;  b.y += n5 + x2.y + y2.y;
            b.z += n6 + x3.x + y3.x;  b.w += n7 + x3.y + y3.y;
            res[rb] = a;
            res[rb + 1] = b;
        }
    }
}

// ---------------- launch ----------------

extern "C" void kernel_launch(void* const* d_in, const int* in_sizes, int n_in,
                              void* d_out, int out_size, void* d_ws, size_t ws_size,
                              hipStream_t stream) {
    const float* user_emb   = (const float*)d_in[0];
    const float* entity_emb = (const float*)d_in[1];
    const float* weight     = (const float*)d_in[2];
    const float* unmask     = (const float*)d_in[3];
    const int*   edge_index = (const int*)d_in[4];
    const int*   edge_type  = (const int*)d_in[5];
    const int*   irows      = (const int*)d_in[6];
    const int*   icols      = (const int*)d_in[7];
    const int* head = edge_index;            // edge_index[0]
    const int* tail = edge_index + N_EDGES;  // edge_index[1]

    char* ws = (char*)d_ws;
    size_t off = 0;
    auto alloc = [&](size_t bytes) -> void* {
        void* p = ws + off;
        off += (bytes + 255) & ~(size_t)255;
        return p;
    };
    uint4* B0     = (uint4*)alloc((size_t)N_ENT * DIM * 2);   // fp16 emb
    uint4* B1     = (uint4*)alloc((size_t)N_ENT * DIM * 2);   // n1 (ent)
    uint4* B2     = (uint4*)alloc((size_t)N_ENT * DIM * 2);   // n2 (ent)
    uint4* U1     = (uint4*)alloc((size_t)N_USERS * DIM * 2); // n1 (usr)
    uint4* U2     = (uint4*)alloc((size_t)N_USERS * DIM * 2); // n2 (usr)
    uint4* w16    = (uint4*)alloc(16 * DIM * 2);
    int*   rp_e   = (int*)alloc((N_ENT + 1) * 4);
    int*   rp_u   = (int*)alloc((N_USERS + 1) * 4);
    long long* ev     = (long long*)alloc((size_t)N_EDGES * 8);
    long long* tmp_ev = (long long*)alloc((size_t)N_EDGES * 8);
    int*   col_s   = (int*)alloc((size_t)NNZ * 4);
    int*   tmp_col = (int*)alloc((size_t)NNZ * 4);
    int*   bh     = (int*)alloc((size_t)(NALL + 1) * 4);
    int*   offA   = (int*)alloc((size_t)(NALL + 1) * 4);
    int*   bs     = (int*)alloc(1024 * 4);
    (void)ws_size;

    // --- fp16 conversions (independent of CSR build) ---
    f32_to_f16<<<(N_ENT * DIM / 8 + 255) / 256, 256, 0, stream>>>(
        (const float4*)entity_emb, B0, N_ENT * DIM / 8);
    f32_to_f16<<<1, 128, 0, stream>>>((const float4*)weight, w16, 16 * DIM / 8);

    // --- CSR build: merged two-level LDS counting sort ---
    bucket_hist_both<<<2 * GA, 256, 0, stream>>>(head, irows, bh);
    scan_partial<<<NB_SCAN, 512, 0, stream>>>(bh, NALL, bs);
    scan_bsum<<<1, 1024, 0, stream>>>(bs, NB_SCAN);
    scan_final<<<NB_SCAN, 512, 0, stream>>>(bh, NALL, bs, offA);
    bucket_scatter_both<<<2 * GA, 256, 0, stream>>>(
        head, tail, edge_type, unmask, irows, icols, offA, tmp_ev, tmp_col);
    bucket_sort_both<<<NB_E + NB_U, 256, 0, stream>>>(
        offA, tmp_ev, tmp_col, ev, col_s, rp_e, rp_u);

    // --- 3 hops: h0,h1 write fp16 outputs; h2 fuses residual sum ---
    float* res_e = (float*)d_out;
    float* res_u = res_e + (size_t)N_ENT * DIM;
    int grid_agg = ((HALF_E + HALF_U) * 64 + 255) / 256;

    agg_hop<0><<<grid_agg, 256, 0, stream>>>(
        B0, w16, rp_e, (const int2*)ev, rp_u, col_s, B1, U1,
        nullptr, nullptr, nullptr, nullptr, nullptr, nullptr, nullptr);
    agg_hop<0><<<grid_agg, 256, 0, stream>>>(
        B1, w16, rp_e, (const int2*)ev, rp_u, col_s, B2, U2,
        nullptr, nullptr, nullptr, nullptr, nullptr, nullptr, nullptr);
    agg_hop<1><<<grid_agg, 256, 0, stream>>>(
        B2, w16, rp_e, (const int2*)ev, rp_u, col_s, nullptr, nullptr,
        B1, U1, U2,
        (const float4*)entity_emb, (const float4*)user_emb,
        (float4*)res_e, (float4*)res_u);
}